// Round 14
// baseline (2487.829 us; speedup 1.0000x reference)
//
#include <hip/hip_runtime.h>
#include <hip/hip_bf16.h>
#include <hip/hip_fp16.h>
#include <stdint.h>

#define D_  256   // emb dim
#define FD_ 512   // feat dim
#define L_  5     // layers
#define EPS_ 1e-5f

// packed-tile format (R6-proven): tile = 128 rows x 32 k, stored as 4 k-planes
// (8 k each): plane = 128 rows x 16B + 64B pad = 2112B. tile = 8448B = 4224 sh.
// element (r,k): plane k>>3, offset r*8 + (k&7) (shorts).
#define PLANE_SH 1056
#define TILE_SH  4224

typedef unsigned short ushort_t;
typedef __attribute__((ext_vector_type(8))) _Float16 h8v;  // 8 f16 (MFMA frag)
typedef __attribute__((ext_vector_type(4))) float    f4v;  // MFMA C/D frag

// numerically-stable softplus == jnp.logaddexp(x, 0) — NATIVE exp/log (R11-proven)
__device__ __forceinline__ float sp(float x) {
    float t = __expf(-fabsf(x));            // native v_exp_f32
    return fmaxf(x, 0.f) + __logf(1.f + t); // native v_log_f32
}

__device__ __forceinline__ ushort_t f2h_bits(float v) {
    union { _Float16 h; ushort_t u; } c;
    c.h = (_Float16)v;
    return c.u;
}

__device__ __forceinline__ float h2f(ushort_t u) {
    union { ushort_t u; _Float16 h; } c;
    c.u = u;
    return (float)c.h;
}

// split fp32 into f16 hi + f16 lo; v ~= hi + lo to ~2^-22 rel
__device__ __forceinline__ void split_f16(float v, ushort_t& hi, ushort_t& lo) {
    union { _Float16 h; ushort_t u; } c;
    c.h = (_Float16)v;
    hi = c.u;
    float rem = v - (float)c.h;
    c.h = (_Float16)rem;
    lo = c.u;
}

// async global->LDS: lds dest = wave-uniform base + lane*16B
__device__ __forceinline__ void gload_lds16(const void* g, void* l) {
    __builtin_amdgcn_global_load_lds((const __attribute__((address_space(1))) void*)g,
                                     (__attribute__((address_space(3))) void*)l,
                                     16, 0, 0);
}

// packed-f16 element offset for (row gm, col gn) with nKB = cols/32
__device__ __forceinline__ size_t pk_off(int gm, int gn, int nKB) {
    return ((size_t)(gm >> 7) * nKB + (gn >> 5)) * TILE_SH
         + (size_t)((gn >> 3) & 3) * PLANE_SH
         + (gm & 127) * 8 + (gn & 7);
}

// ---------------------------------------------------------------------------
// h16[i,d] = f16( x_emb1[atomics[i],d] + pos[i,:] @ x_emb2_w[:,d] + x_emb2_b[d] )
// (raw pre-BN node features, f16 row-major) [R14]
// ---------------------------------------------------------------------------
__global__ __launch_bounds__(256)
void init_h_kernel(const int* __restrict__ atomics, const float* __restrict__ pos,
                   const float* __restrict__ emb1, const float* __restrict__ w2,
                   const float* __restrict__ b2, ushort_t* __restrict__ h16, int N)
{
    int i = blockIdx.x;
    int d = threadIdx.x;
    int a = atomics[i];
    float p0 = pos[(size_t)i * 3 + 0];
    float p1 = pos[(size_t)i * 3 + 1];
    float p2 = pos[(size_t)i * 3 + 2];
    float v = emb1[(size_t)a * D_ + d]
            + p0 * w2[0 * D_ + d]
            + p1 * w2[1 * D_ + d]
            + p2 * w2[2 * D_ + d]
            + b2[d];
    h16[(size_t)i * D_ + d] = f2h_bits(v);
}

// ---------------------------------------------------------------------------
// CSR build (unordered segments; segment order irrelevant)
// ---------------------------------------------------------------------------
__global__ __launch_bounds__(256)
void hist_kernel(const int* __restrict__ dst, int* __restrict__ cnt, int E)
{
    int e = blockIdx.x * 256 + threadIdx.x;
    if (e < E) atomicAdd(&cnt[dst[e]], 1);
}

__global__ __launch_bounds__(256)
void alloc_kernel(const int* __restrict__ cnt, int* __restrict__ start,
                  int* __restrict__ cursor, int* __restrict__ total, int N)
{
    int i = blockIdx.x * 256 + threadIdx.x;
    if (i < N) {
        int s = atomicAdd(total, cnt[i]);
        start[i] = s;
        cursor[i] = s;
    }
}

__global__ __launch_bounds__(256)
void fill_kernel(const int* __restrict__ src, const int* __restrict__ dst,
                 const int* __restrict__ attr, int* __restrict__ cursor,
                 uint32_t* __restrict__ elist, int E)
{
    int e = blockIdx.x * 256 + threadIdx.x;
    if (e < E) {
        int p = atomicAdd(&cursor[dst[e]], 1);
        elist[p] = (uint32_t)src[e] | ((uint32_t)attr[e] << 30);
    }
}

// ---------------------------------------------------------------------------
// gather_pack [R14]: act(x) = BN-affine + softplus of PREVIOUS layer folded in
// (bnsum==null -> identity, layer 0).  Thread owns fixed channel d, so
// scale/shift are computed ONCE, then 1 fma + native-sp per gathered element.
// agg[i,:] = act(h[i,:]) + ee_l[1,:] + sum_{e:dst=i}(act(h[src_e,:]) + ee_l[attr_e,:])
// writes agg DIRECTLY in packed-f16 tile format.
// ---------------------------------------------------------------------------
__global__ __launch_bounds__(256)
void gather_pack_kernel(const ushort_t* __restrict__ h16, const uint32_t* __restrict__ elist,
                        const int* __restrict__ start, const int* __restrict__ cnt,
                        const float* __restrict__ ee_l, ushort_t* __restrict__ aggP,
                        const float* __restrict__ bnsum, const float* __restrict__ gamma,
                        const float* __restrict__ beta, float invN, int N)
{
    int i = blockIdx.x;
    int d = threadIdx.x;
    float sc = 1.f, sh = 0.f;
    const bool act = (bnsum != nullptr);
    if (act) {
        float mean = bnsum[d] * invN;
        float var = bnsum[D_ + d] * invN - mean * mean;
        sc = gamma[d] * rsqrtf(fmaxf(var, 0.f) + EPS_);
        sh = beta[d] - mean * sc;
    }
    float x0 = h2f(h16[(size_t)i * D_ + d]);
    if (act) x0 = sp(x0 * sc + sh);
    float acc = x0 + ee_l[D_ + d];                      // self-loop (bond 1)
    int base = start[i], deg = cnt[i];
    for (int j = 0; j < deg; ++j) {
        uint32_t p = elist[base + j];
        int s = p & 0x3FFFFFFF;
        int a = p >> 30;
        float x = h2f(h16[(size_t)s * D_ + d]);
        if (act) x = sp(x * sc + sh);
        acc += x + ee_l[a * D_ + d];
    }
    aggP[pk_off(i, d, 8)] = f2h_bits(acc);
}

// bn_pack: BN affine (no softplus) of last layer -> packed f16 (feeds feat gemm)
__global__ __launch_bounds__(256)
void bn_pack_kernel(const ushort_t* __restrict__ h16, const float* __restrict__ bnsum,
                    const float* __restrict__ gamma, const float* __restrict__ beta,
                    ushort_t* __restrict__ outP, int N, float invN)
{
    int i = blockIdx.x;
    int d = threadIdx.x;
    float mean = bnsum[d] * invN;
    float var = bnsum[D_ + d] * invN - mean * mean;
    float inv = 1.f / sqrtf(fmaxf(var, 0.f) + EPS_);
    float v = (h2f(h16[(size_t)i * D_ + d]) - mean) * inv * gamma[d] + beta[d];
    outP[pk_off(i, d, 8)] = f2h_bits(v);
}

// ---------------------------------------------------------------------------
// weight pack: W fp32 [K][N] -> split-f16 tiles (nb, kb), tile row = col n
// grid (nKB, nNB)
// ---------------------------------------------------------------------------
__global__ __launch_bounds__(256)
void convert_w_pack(const float* __restrict__ W, ushort_t* __restrict__ dh,
                    ushort_t* __restrict__ dl, int N, int nKB)
{
    int kb = blockIdx.x, nb = blockIdx.y;
    int n = threadIdx.x >> 1, half = threadIdx.x & 1;
#pragma unroll
    for (int j = 0; j < 2; ++j) {
        int kq = half * 2 + j;
        size_t o = (size_t)(nb * nKB + kb) * TILE_SH + kq * PLANE_SH + n * 8;
#pragma unroll
        for (int jj = 0; jj < 8; ++jj) {
            float w = W[(size_t)(kb * 32 + kq * 8 + jj) * N + nb * 128 + n];
            ushort_t hi, lo;
            split_f16(w, hi, lo);
            dh[o + jj] = hi;
            dl[o + jj] = lo;
        }
    }
}

// ---------------------------------------------------------------------------
// gemm_p16<EPI>: C[m,N] = epi(A[m,K] @ B + bias), all operands packed tiles.
//   A: packed f16 (single).  B: packed split-f16 (hi+lo). 2-term f16 MFMA.
//   R13-proven: two K-tiles staged per barrier round (kb += 2).
//   EPI 0: softplus -> packed f16 Tout (nKBo = N/32)
//   EPI 1: f16 row-major Tout[m][N] (raw h) + fused bn partial sums (N == 256)
//   EPI 2: run-merged atomicAdd into Cout[batch[gm]*N + gn]  (graph pool)
// grid (N/128, mb); block 256 thr / 4 waves (2x2 of 64x64); tile 128x128.
// ---------------------------------------------------------------------------
template <int EPI>
__global__ __launch_bounds__(256)
void gemm_p16(const ushort_t* __restrict__ APK,
              const ushort_t* __restrict__ BPh, const ushort_t* __restrict__ BPl,
              const float* __restrict__ bias,
              ushort_t* __restrict__ Tout, float* __restrict__ Cout,
              float* __restrict__ bnsum, const int* __restrict__ batch,
              int m, int N, int nKB)
{
    __shared__ ushort_t lA[2 * TILE_SH], lBh[2 * TILE_SH], lBl[2 * TILE_SH]; // 50.7 KB

    int tid = threadIdx.x, wave = tid >> 6, lane = tid & 63;
    int nb = blockIdx.x, rb = blockIdx.y;
    int wr = wave >> 1, wc = wave & 1;
    int fr = lane & 15, kq = lane >> 4;

    f4v acc[4][4];
#pragma unroll
    for (int i = 0; i < 4; ++i)
#pragma unroll
        for (int j = 0; j < 4; ++j)
            acc[i][j] = (f4v){0.f, 0.f, 0.f, 0.f};

    for (int kb = 0; kb < nKB; kb += 2) {
        // two consecutive k-tiles are contiguous in the packed layout
        const ushort_t* as = APK + (size_t)(rb * nKB + kb) * TILE_SH;
        const ushort_t* bh = BPh + (size_t)(nb * nKB + kb) * TILE_SH;
        const ushort_t* bl = BPl + (size_t)(nb * nKB + kb) * TILE_SH;
        for (int c = tid; c < 1056; c += 256) {
            int base = (c - lane) * 8;   // wave-uniform LDS base
            gload_lds16(as + c * 8, lA + base);
            gload_lds16(bh + c * 8, lBh + base);
            gload_lds16(bl + c * 8, lBl + base);
        }
        __syncthreads();

#pragma unroll
        for (int sub = 0; sub < 2; ++sub) {
            const ushort_t* sA = lA + sub * TILE_SH;
            const ushort_t* sBh = lBh + sub * TILE_SH;
            const ushort_t* sBl = lBl + sub * TILE_SH;
            h8v Af[4], Bh4[4], Bl4[4];
#pragma unroll
            for (int t = 0; t < 4; ++t) {
                int ao = kq * PLANE_SH + (wr * 64 + fr + t * 16) * 8;
                int bo = kq * PLANE_SH + (wc * 64 + fr + t * 16) * 8;
                Af[t]  = *(const h8v*)(sA + ao);
                Bh4[t] = *(const h8v*)(sBh + bo);
                Bl4[t] = *(const h8v*)(sBl + bo);
            }
#pragma unroll
            for (int rt = 0; rt < 4; ++rt)
#pragma unroll
                for (int ct = 0; ct < 4; ++ct) {
                    acc[rt][ct] = __builtin_amdgcn_mfma_f32_16x16x32_f16(Af[rt], Bh4[ct], acc[rt][ct], 0, 0, 0);
                    acc[rt][ct] = __builtin_amdgcn_mfma_f32_16x16x32_f16(Af[rt], Bl4[ct], acc[rt][ct], 0, 0, 0);
                }
        }
        __syncthreads();
    }

    // epilogue: C/D layout col = lane&15, row = (lane>>4)*4 + reg
    int gm00 = rb * 128 + wr * 64 + kq * 4;
    int gn0  = nb * 128 + wc * 64 + fr;
    int nKBo = N >> 5;
#pragma unroll
    for (int ct = 0; ct < 4; ++ct) {
        int gn = gn0 + ct * 16;
        float bv = bias[gn];
        float s = 0.f, ss = 0.f;
#pragma unroll
        for (int rt = 0; rt < 4; ++rt) {
            if (EPI == 2) {
                int bp = -1; float run = 0.f;
#pragma unroll
                for (int rr = 0; rr < 4; ++rr) {
                    int gm = gm00 + rt * 16 + rr;
                    if (gm >= m) continue;
                    float v = acc[rt][ct][rr] + bv;
                    int bg = batch[gm];
                    if (bg == bp) { run += v; }
                    else {
                        if (bp >= 0) atomicAdd(&Cout[(size_t)bp * N + gn], run);
                        bp = bg; run = v;
                    }
                }
                if (bp >= 0) atomicAdd(&Cout[(size_t)bp * N + gn], run);
            } else {
#pragma unroll
                for (int rr = 0; rr < 4; ++rr) {
                    int gm = gm00 + rt * 16 + rr;
                    if (gm >= m) continue;
                    float v = acc[rt][ct][rr] + bv;
                    if (EPI == 0) {
                        Tout[pk_off(gm, gn, nKBo)] = f2h_bits(sp(v));
                    } else {
                        Tout[(size_t)gm * N + gn] = f2h_bits(v);  // raw h, f16 [R14]
                        s += v;
                        ss += v * v;
                    }
                }
            }
        }
        if (EPI == 1) {
            s  += __shfl_xor(s, 16);  s  += __shfl_xor(s, 32);
            ss += __shfl_xor(ss, 16); ss += __shfl_xor(ss, 32);
            if (kq == 0) {
                atomicAdd(&bnsum[gn], s);
                atomicAdd(&bnsum[D_ + gn], ss);
            }
        }
    }
}

// ---------------------------------------------------------------------------
__global__ __launch_bounds__(256)
void count_kernel(const int* __restrict__ batch, float* __restrict__ cnt, int N)
{
    int i = blockIdx.x * 256 + threadIdx.x;
    if (i < N) atomicAdd(&cnt[batch[i]], 1.f);
}

__global__ __launch_bounds__(256)
void pool_div_kernel(float* __restrict__ gfeat, const float* __restrict__ cnt, int G)
{
    int g = blockIdx.x;
    float inv = 1.f / fmaxf(cnt[g], 1.f);
    for (int c = threadIdx.x; c < FD_; c += 256)
        gfeat[(size_t)g * FD_ + c] *= inv;
}

// ---------------------------------------------------------------------------
// fp32 GEMM for the small head: C = softplus(A @ W + bias)
// ---------------------------------------------------------------------------
#define BM 64
#define BN 64
#define BK 16

__global__ __launch_bounds__(256)
void gemm_head(const float* __restrict__ A, const float* __restrict__ W,
               const float* __restrict__ bias, float* __restrict__ C,
               int M, int N, int K)
{
    __shared__ float As[BK][BM + 4];
    __shared__ float Ws[BK][BN + 4];

    int tid = threadIdx.x;
    int bm = blockIdx.y * BM;
    int bn = blockIdx.x * BN;
    int tx = tid & 15;
    int ty = tid >> 4;

    float acc[4][4] = {};

    int a_m = tid >> 2;
    int a_k = (tid & 3) * 4;
    int w_k = tid >> 4;
    int w_n = (tid & 15) * 4;

    for (int k0 = 0; k0 < K; k0 += BK) {
        int gm = bm + a_m;
        float4 av = make_float4(0.f, 0.f, 0.f, 0.f);
        if (gm < M)
            av = *(const float4*)(A + (size_t)gm * K + k0 + a_k);
        As[a_k + 0][a_m] = av.x;
        As[a_k + 1][a_m] = av.y;
        As[a_k + 2][a_m] = av.z;
        As[a_k + 3][a_m] = av.w;

        float4 wv = *(const float4*)(W + (size_t)(k0 + w_k) * N + bn + w_n);
        *(float4*)&Ws[w_k][w_n] = wv;

        __syncthreads();

#pragma unroll
        for (int k = 0; k < BK; ++k) {
            float4 a4 = *(const float4*)&As[k][ty * 4];
            float4 b4 = *(const float4*)&Ws[k][tx * 4];
            float a[4] = {a4.x, a4.y, a4.z, a4.w};
            float b[4] = {b4.x, b4.y, b4.z, b4.w};
#pragma unroll
            for (int i = 0; i < 4; ++i)
#pragma unroll
                for (int j = 0; j < 4; ++j)
                    acc[i][j] += a[i] * b[j];
        }
        __syncthreads();
    }

#pragma unroll
    for (int i = 0; i < 4; ++i) {
        int gm = bm + ty * 4 + i;
        if (gm >= M) continue;
#pragma unroll
        for (int j = 0; j < 4; ++j) {
            int gn = bn + tx * 4 + j;
            C[(size_t)gm * N + gn] = sp(acc[i][j] + bias[gn]);
        }
    }
}

__global__ __launch_bounds__(256)
void head2_kernel(const float* __restrict__ hid, const float* __restrict__ w2,
                  const float* __restrict__ b2, float* __restrict__ out, int G)
{
    __shared__ float red[256];
    int g = blockIdx.x;
    int t = threadIdx.x;
    float v = hid[(size_t)g * 256 + t] * w2[t];
    red[t] = v;
    __syncthreads();
    for (int s = 128; s > 0; s >>= 1) {
        if (t < s) red[t] += red[t + s];
        __syncthreads();
    }
    if (t == 0) out[g] = red[0] + b2[0];
}

// ---------------------------------------------------------------------------
extern "C" void kernel_launch(void* const* d_in, const int* in_sizes, int n_in,
                              void* d_out, int out_size, void* d_ws, size_t ws_size,
                              hipStream_t stream)
{
    const int N = in_sizes[0];
    const int E = in_sizes[3];
    const int G = out_size;

    const int*   atomics  = (const int*)d_in[0];
    const float* pos      = (const float*)d_in[1];
    const int*   eidx     = (const int*)d_in[2];
    const int*   eattr    = (const int*)d_in[3];
    const int*   batch    = (const int*)d_in[4];
    const float* x_emb1   = (const float*)d_in[5];
    const float* x_emb2_w = (const float*)d_in[6];
    const float* x_emb2_b = (const float*)d_in[7];
    const float* edge_emb = (const float*)d_in[8];
    const float* mlp_w1   = (const float*)d_in[9];
    const float* mlp_b1   = (const float*)d_in[10];
    const float* mlp_w2   = (const float*)d_in[11];
    const float* mlp_b2   = (const float*)d_in[12];
    const float* bn_g     = (const float*)d_in[13];
    const float* bn_b     = (const float*)d_in[14];
    const float* feat_w   = (const float*)d_in[15];
    const float* feat_b   = (const float*)d_in[16];
    const float* head_w1  = (const float*)d_in[17];
    const float* head_b1  = (const float*)d_in[18];
    const float* head_w2  = (const float*)d_in[19];
    const float* head_b2  = (const float*)d_in[20];
    float* out = (float*)d_out;

    const int* src = eidx;
    const int* dst = eidx + E;

    char* ws = (char*)d_ws;
    size_t off = 0;
    auto carve = [&](size_t bytes) {
        void* p = ws + off;
        off += (bytes + 255) & ~(size_t)255;
        return p;
    };

    const int nRB = (N + 127) / 128;           // 128-row tiles

    // ---- fixed carve (~130 MB) ----
    ushort_t* h16 = (ushort_t*)carve((size_t)N * D_ * 2);              // 51.2 MB [R14]
    ushort_t* aggP = (ushort_t*)carve((size_t)nRB * 8 * TILE_SH * 2);  // 52.9 MB
    const size_t WTILES = 32 * TILE_SH;
    ushort_t* w1Ph = (ushort_t*)carve((size_t)L_ * WTILES * 2);
    ushort_t* w1Pl = (ushort_t*)carve((size_t)L_ * WTILES * 2);
    ushort_t* w2Ph = (ushort_t*)carve((size_t)L_ * WTILES * 2);
    ushort_t* w2Pl = (ushort_t*)carve((size_t)L_ * WTILES * 2);
    ushort_t* fPh  = (ushort_t*)carve(WTILES * 2);
    ushort_t* fPl  = (ushort_t*)carve(WTILES * 2);
    float* bnsum   = (float*)carve(2 * D_ * 4);
    float* gfeat   = (float*)carve((size_t)G * FD_ * 4);               // 8.2 MB
    float* cnt     = (float*)carve((size_t)G * 4);
    float* hid     = (float*)carve((size_t)G * (FD_ / 2) * 4);
    // CSR buffers (~5 MB)
    int* cnt_i   = (int*)carve((size_t)N * 4);
    int* start_i = (int*)carve((size_t)N * 4);
    int* cursor  = (int*)carve((size_t)N * 4);
    int* total   = (int*)carve(4);
    uint32_t* elist = (uint32_t*)carve((size_t)E * 4);

    // ---- adaptive chunk for packed f16 T (16 tiles x 8448 B per 128 rows) ----
    size_t avail = (ws_size > off + 4096) ? (ws_size - off - 4096) : 0;
    long long mcb = (long long)(avail / (16 * (size_t)TILE_SH * 2));
    if (mcb > nRB) mcb = nRB;
    if (mcb < 16) mcb = 16;                    // floor (ws proven >= this)
    const int Mc = (int)(mcb * 128);
    ushort_t* tP = (ushort_t*)carve((size_t)mcb * 16 * TILE_SH * 2);

    const float invN = 1.f / (float)N;

    // ---- CSR build (once per launch, reused all 5 layers) ----
    hipMemsetAsync(cnt_i, 0, (size_t)N * 4, stream);
    hipMemsetAsync(total, 0, 4, stream);
    hist_kernel<<<(E + 255) / 256, 256, 0, stream>>>(dst, cnt_i, E);
    alloc_kernel<<<(N + 255) / 256, 256, 0, stream>>>(cnt_i, start_i, cursor, total, N);
    fill_kernel<<<(E + 255) / 256, 256, 0, stream>>>(src, dst, eattr, cursor, elist, E);

    // ---- one-time weight packing (all split f16) ----
    for (int l = 0; l < L_; ++l) {
        convert_w_pack<<<dim3(8, 4), 256, 0, stream>>>(
            mlp_w1 + (size_t)l * D_ * FD_, w1Ph + (size_t)l * WTILES,
            w1Pl + (size_t)l * WTILES, FD_, 8);
        convert_w_pack<<<dim3(16, 2), 256, 0, stream>>>(
            mlp_w2 + (size_t)l * FD_ * D_, w2Ph + (size_t)l * WTILES,
            w2Pl + (size_t)l * WTILES, D_, 16);
    }
    convert_w_pack<<<dim3(8, 4), 256, 0, stream>>>(feat_w, fPh, fPl, FD_, 8);

    init_h_kernel<<<N, 256, 0, stream>>>(atomics, pos, x_emb1, x_emb2_w, x_emb2_b, h16, N);

    for (int l = 0; l < L_; ++l) {
        const float* ee_l = edge_emb + (size_t)l * 2 * D_;
        // aggregation with previous layer's BN+softplus folded in (null for l=0)
        const float* bs_prev = (l == 0) ? nullptr : bnsum;
        const float* g_prev  = bn_g + (size_t)(l > 0 ? l - 1 : 0) * D_;
        const float* b_prev  = bn_b + (size_t)(l > 0 ? l - 1 : 0) * D_;
        gather_pack_kernel<<<N, 256, 0, stream>>>(h16, elist, start_i, cnt_i, ee_l,
                                                  aggP, bs_prev, g_prev, b_prev, invN, N);

        hipMemsetAsync(bnsum, 0, 2 * D_ * 4, stream);
        for (int r0 = 0; r0 < N; r0 += Mc) {
            int m = min(Mc, N - r0);
            int mb = (m + 127) / 128;
            // T = sp(agg @ W1 + b1)  -> packed f16
            gemm_p16<0><<<dim3(4, mb), 256, 0, stream>>>(
                aggP + (size_t)(r0 >> 7) * 8 * TILE_SH,
                w1Ph + (size_t)l * WTILES, w1Pl + (size_t)l * WTILES,
                mlp_b1 + (size_t)l * FD_, tP, nullptr, nullptr, nullptr,
                m, FD_, 8);
            // h16 = f16(T @ W2 + b2) raw + bn stats
            gemm_p16<1><<<dim3(2, mb), 256, 0, stream>>>(
                tP, w2Ph + (size_t)l * WTILES, w2Pl + (size_t)l * WTILES,
                mlp_b2 + (size_t)l * D_, h16 + (size_t)r0 * D_, nullptr, bnsum, nullptr,
                m, D_, 16);
        }
    }

    // ---- feat + mean-pool: BN(h16) -> packed f16 (reuse aggP), pooled gemm ----
    bn_pack_kernel<<<N, 256, 0, stream>>>(h16, bnsum, bn_g + (size_t)(L_ - 1) * D_,
                                          bn_b + (size_t)(L_ - 1) * D_, aggP, N, invN);
    hipMemsetAsync(gfeat, 0, (size_t)G * FD_ * 4, stream);
    hipMemsetAsync(cnt, 0, (size_t)G * 4, stream);
    gemm_p16<2><<<dim3(4, nRB), 256, 0, stream>>>(
        aggP, fPh, fPl, feat_b, nullptr, gfeat, nullptr, batch, N, FD_, 8);
    count_kernel<<<(N + 255) / 256, 256, 0, stream>>>(batch, cnt, N);
    pool_div_kernel<<<G, 256, 0, stream>>>(gfeat, cnt, G);

    // ---- head ----
    gemm_head<<<dim3((FD_ / 2) / BN, (G + BM - 1) / BM), 256, 0, stream>>>(
        gfeat, head_w1, head_b1, hid, G, FD_ / 2, FD_);
    head2_kernel<<<G, 256, 0, stream>>>(hid, head_w2, head_b2, out, G);
}

// Round 15
// 2202.664 us; speedup vs baseline: 1.1295x; 1.1295x over previous
//
#include <hip/hip_runtime.h>
#include <hip/hip_bf16.h>
#include <hip/hip_fp16.h>
#include <stdint.h>

#define D_  256   // emb dim
#define FD_ 512   // feat dim
#define L_  5     // layers
#define EPS_ 1e-5f

// packed-tile format (R6-proven): tile = 128 rows x 32 k, stored as 4 k-planes
// (8 k each): plane = 128 rows x 16B + 64B pad = 2112B. tile = 8448B = 4224 sh.
#define PLANE_SH 1056
#define TILE_SH  4224

typedef unsigned short ushort_t;
typedef __attribute__((ext_vector_type(8))) _Float16 h8v;  // 8 f16 (MFMA frag)
typedef __attribute__((ext_vector_type(4))) float    f4v;  // MFMA C/D frag

// numerically-stable softplus == jnp.logaddexp(x, 0) — NATIVE exp/log (R11-proven)
__device__ __forceinline__ float sp(float x) {
    float t = __expf(-fabsf(x));            // native v_exp_f32
    return fmaxf(x, 0.f) + __logf(1.f + t); // native v_log_f32
}

__device__ __forceinline__ ushort_t f2h_bits(float v) {
    union { _Float16 h; ushort_t u; } c;
    c.h = (_Float16)v;
    return c.u;
}

__device__ __forceinline__ float h2f(ushort_t u) {
    union { ushort_t u; _Float16 h; } c;
    c.u = u;
    return (float)c.h;
}

// split fp32 into f16 hi + f16 lo; v ~= hi + lo to ~2^-22 rel
__device__ __forceinline__ void split_f16(float v, ushort_t& hi, ushort_t& lo) {
    union { _Float16 h; ushort_t u; } c;
    c.h = (_Float16)v;
    hi = c.u;
    float rem = v - (float)c.h;
    c.h = (_Float16)rem;
    lo = c.u;
}

// async global->LDS: lds dest = wave-uniform base + lane*16B
__device__ __forceinline__ void gload_lds16(const void* g, void* l) {
    __builtin_amdgcn_global_load_lds((const __attribute__((address_space(1))) void*)g,
                                     (__attribute__((address_space(3))) void*)l,
                                     16, 0, 0);
}

// packed-f16 element offset for (row gm, col gn) with nKB = cols/32
__device__ __forceinline__ size_t pk_off(int gm, int gn, int nKB) {
    return ((size_t)(gm >> 7) * nKB + (gn >> 5)) * TILE_SH
         + (size_t)((gn >> 3) & 3) * PLANE_SH
         + (gm & 127) * 8 + (gn & 7);
}

// ---------------------------------------------------------------------------
// h16[i,d] = f16( x_emb1[atomics[i],d] + pos[i,:] @ x_emb2_w[:,d] + x_emb2_b[d] )
// ---------------------------------------------------------------------------
__global__ __launch_bounds__(256)
void init_h_kernel(const int* __restrict__ atomics, const float* __restrict__ pos,
                   const float* __restrict__ emb1, const float* __restrict__ w2,
                   const float* __restrict__ b2, ushort_t* __restrict__ h16, int N)
{
    int i = blockIdx.x;
    int d = threadIdx.x;
    int a = atomics[i];
    float p0 = pos[(size_t)i * 3 + 0];
    float p1 = pos[(size_t)i * 3 + 1];
    float p2 = pos[(size_t)i * 3 + 2];
    float v = emb1[(size_t)a * D_ + d]
            + p0 * w2[0 * D_ + d]
            + p1 * w2[1 * D_ + d]
            + p2 * w2[2 * D_ + d]
            + b2[d];
    h16[(size_t)i * D_ + d] = f2h_bits(v);
}

// ---------------------------------------------------------------------------
// CSR build (unordered segments; segment order irrelevant)
// ---------------------------------------------------------------------------
__global__ __launch_bounds__(256)
void hist_kernel(const int* __restrict__ dst, int* __restrict__ cnt, int E)
{
    int e = blockIdx.x * 256 + threadIdx.x;
    if (e < E) atomicAdd(&cnt[dst[e]], 1);
}

__global__ __launch_bounds__(256)
void alloc_kernel(const int* __restrict__ cnt, int* __restrict__ start,
                  int* __restrict__ cursor, int* __restrict__ total, int N)
{
    int i = blockIdx.x * 256 + threadIdx.x;
    if (i < N) {
        int s = atomicAdd(total, cnt[i]);
        start[i] = s;
        cursor[i] = s;
    }
}

__global__ __launch_bounds__(256)
void fill_kernel(const int* __restrict__ src, const int* __restrict__ dst,
                 const int* __restrict__ attr, int* __restrict__ cursor,
                 uint32_t* __restrict__ elist, int E)
{
    int e = blockIdx.x * 256 + threadIdx.x;
    if (e < E) {
        int p = atomicAdd(&cursor[dst[e]], 1);
        elist[p] = (uint32_t)src[e] | ((uint32_t)attr[e] << 30);
    }
}

// ---------------------------------------------------------------------------
// act16 [R15]: hact = f16( sp( BN-affine(h16) ) ), vectorized 8 ch/thread.
// Activation computed ONCE per node element (R14 recomputed it per edge).
// ---------------------------------------------------------------------------
__global__ __launch_bounds__(256)
void act16_kernel(const ushort_t* __restrict__ h16, ushort_t* __restrict__ hact,
                  const float* __restrict__ bnsum, const float* __restrict__ gamma,
                  const float* __restrict__ beta, long long total8, float invN)
{
    __shared__ float ssc[256], ssh[256];
    int t = threadIdx.x;
    {
        float mean = bnsum[t] * invN;
        float var = bnsum[D_ + t] * invN - mean * mean;
        float sc = gamma[t] * rsqrtf(fmaxf(var, 0.f) + EPS_);
        ssc[t] = sc;
        ssh[t] = beta[t] - mean * sc;
    }
    __syncthreads();
    long long idx = (long long)blockIdx.x * 256 + t;
    if (idx >= total8) return;
    int c0 = (int)((idx * 8) & 255);           // 8 consecutive channels
    uint4 in = *(const uint4*)(h16 + idx * 8); // 8 ushorts
    ushort_t* ip = (ushort_t*)&in;
    ushort_t ov[8];
#pragma unroll
    for (int j = 0; j < 8; ++j)
        ov[j] = f2h_bits(sp(h2f(ip[j]) * ssc[c0 + j] + ssh[c0 + j]));
    *(uint4*)(hact + idx * 8) = *(uint4*)ov;
}

// ---------------------------------------------------------------------------
// gather_pack4 [R15]: 4 rows per block -> packed writes tile full 64-B lines
// (kills the R14 2x write amplification). Pure sum: activation pre-applied.
// agg[i,:] = hact[i,:] + ee_l[1,:] + sum_{e:dst=i}(hact[src_e,:] + ee_l[attr_e,:])
// ---------------------------------------------------------------------------
__global__ __launch_bounds__(256)
void gather_pack4_kernel(const ushort_t* __restrict__ hact, const uint32_t* __restrict__ elist,
                         const int* __restrict__ start, const int* __restrict__ cnt,
                         const float* __restrict__ ee_l, ushort_t* __restrict__ aggP, int N)
{
    int i0 = blockIdx.x * 4;
    int d = threadIdx.x;
    float ee0 = ee_l[d];        // bond 0
    float ee1 = ee_l[D_ + d];   // bond 1 (also self-loop)
    float acc[4];
#pragma unroll
    for (int r = 0; r < 4; ++r) {
        int i = i0 + r;
        if (i >= N) { acc[r] = 0.f; continue; }
        float a = h2f(hact[(size_t)i * D_ + d]) + ee1;
        int base = start[i], deg = cnt[i];
        for (int j = 0; j < deg; ++j) {
            uint32_t p = elist[base + j];
            int s = p & 0x3FFFFFFF;
            a += h2f(hact[(size_t)s * D_ + d]) + ((p >> 30) ? ee1 : ee0);
        }
        acc[r] = a;
    }
#pragma unroll
    for (int r = 0; r < 4; ++r) {
        int i = i0 + r;
        if (i < N) aggP[pk_off(i, d, 8)] = f2h_bits(acc[r]);
    }
}

// bn_pack: BN affine (no softplus) of last layer -> packed f16 (feeds feat gemm)
__global__ __launch_bounds__(256)
void bn_pack_kernel(const ushort_t* __restrict__ h16, const float* __restrict__ bnsum,
                    const float* __restrict__ gamma, const float* __restrict__ beta,
                    ushort_t* __restrict__ outP, int N, float invN)
{
    int i = blockIdx.x;
    int d = threadIdx.x;
    float mean = bnsum[d] * invN;
    float var = bnsum[D_ + d] * invN - mean * mean;
    float inv = 1.f / sqrtf(fmaxf(var, 0.f) + EPS_);
    float v = (h2f(h16[(size_t)i * D_ + d]) - mean) * inv * gamma[d] + beta[d];
    outP[pk_off(i, d, 8)] = f2h_bits(v);
}

// ---------------------------------------------------------------------------
// weight pack: W fp32 [K][N] -> split-f16 tiles (nb, kb), tile row = col n
// ---------------------------------------------------------------------------
__global__ __launch_bounds__(256)
void convert_w_pack(const float* __restrict__ W, ushort_t* __restrict__ dh,
                    ushort_t* __restrict__ dl, int N, int nKB)
{
    int kb = blockIdx.x, nb = blockIdx.y;
    int n = threadIdx.x >> 1, half = threadIdx.x & 1;
#pragma unroll
    for (int j = 0; j < 2; ++j) {
        int kq = half * 2 + j;
        size_t o = (size_t)(nb * nKB + kb) * TILE_SH + kq * PLANE_SH + n * 8;
#pragma unroll
        for (int jj = 0; jj < 8; ++jj) {
            float w = W[(size_t)(kb * 32 + kq * 8 + jj) * N + nb * 128 + n];
            ushort_t hi, lo;
            split_f16(w, hi, lo);
            dh[o + jj] = hi;
            dl[o + jj] = lo;
        }
    }
}

// ---------------------------------------------------------------------------
// gemm_p16<EPI> (R13-proven): 2 K-tiles per barrier round.
//   EPI 0: softplus -> packed f16 Tout (nKBo = N/32)
//   EPI 1: f16 row-major Tout[m][N] (raw h) + fused bn partial sums (N == 256)
//   EPI 2: run-merged atomicAdd into Cout[batch[gm]*N + gn]  (graph pool)
// grid (N/128, mb); block 256 thr / 4 waves (2x2 of 64x64); tile 128x128.
// ---------------------------------------------------------------------------
template <int EPI>
__global__ __launch_bounds__(256)
void gemm_p16(const ushort_t* __restrict__ APK,
              const ushort_t* __restrict__ BPh, const ushort_t* __restrict__ BPl,
              const float* __restrict__ bias,
              ushort_t* __restrict__ Tout, float* __restrict__ Cout,
              float* __restrict__ bnsum, const int* __restrict__ batch,
              int m, int N, int nKB)
{
    __shared__ ushort_t lA[2 * TILE_SH], lBh[2 * TILE_SH], lBl[2 * TILE_SH]; // 50.7 KB

    int tid = threadIdx.x, wave = tid >> 6, lane = tid & 63;
    int nb = blockIdx.x, rb = blockIdx.y;
    int wr = wave >> 1, wc = wave & 1;
    int fr = lane & 15, kq = lane >> 4;

    f4v acc[4][4];
#pragma unroll
    for (int i = 0; i < 4; ++i)
#pragma unroll
        for (int j = 0; j < 4; ++j)
            acc[i][j] = (f4v){0.f, 0.f, 0.f, 0.f};

    for (int kb = 0; kb < nKB; kb += 2) {
        const ushort_t* as = APK + (size_t)(rb * nKB + kb) * TILE_SH;
        const ushort_t* bh = BPh + (size_t)(nb * nKB + kb) * TILE_SH;
        const ushort_t* bl = BPl + (size_t)(nb * nKB + kb) * TILE_SH;
        for (int c = tid; c < 1056; c += 256) {
            int base = (c - lane) * 8;   // wave-uniform LDS base
            gload_lds16(as + c * 8, lA + base);
            gload_lds16(bh + c * 8, lBh + base);
            gload_lds16(bl + c * 8, lBl + base);
        }
        __syncthreads();

#pragma unroll
        for (int sub = 0; sub < 2; ++sub) {
            const ushort_t* sA = lA + sub * TILE_SH;
            const ushort_t* sBh = lBh + sub * TILE_SH;
            const ushort_t* sBl = lBl + sub * TILE_SH;
            h8v Af[4], Bh4[4], Bl4[4];
#pragma unroll
            for (int t = 0; t < 4; ++t) {
                int ao = kq * PLANE_SH + (wr * 64 + fr + t * 16) * 8;
                int bo = kq * PLANE_SH + (wc * 64 + fr + t * 16) * 8;
                Af[t]  = *(const h8v*)(sA + ao);
                Bh4[t] = *(const h8v*)(sBh + bo);
                Bl4[t] = *(const h8v*)(sBl + bo);
            }
#pragma unroll
            for (int rt = 0; rt < 4; ++rt)
#pragma unroll
                for (int ct = 0; ct < 4; ++ct) {
                    acc[rt][ct] = __builtin_amdgcn_mfma_f32_16x16x32_f16(Af[rt], Bh4[ct], acc[rt][ct], 0, 0, 0);
                    acc[rt][ct] = __builtin_amdgcn_mfma_f32_16x16x32_f16(Af[rt], Bl4[ct], acc[rt][ct], 0, 0, 0);
                }
        }
        __syncthreads();
    }

    // epilogue: C/D layout col = lane&15, row = (lane>>4)*4 + reg
    int gm00 = rb * 128 + wr * 64 + kq * 4;
    int gn0  = nb * 128 + wc * 64 + fr;
    int nKBo = N >> 5;
#pragma unroll
    for (int ct = 0; ct < 4; ++ct) {
        int gn = gn0 + ct * 16;
        float bv = bias[gn];
        float s = 0.f, ss = 0.f;
#pragma unroll
        for (int rt = 0; rt < 4; ++rt) {
            if (EPI == 2) {
                int bp = -1; float run = 0.f;
#pragma unroll
                for (int rr = 0; rr < 4; ++rr) {
                    int gm = gm00 + rt * 16 + rr;
                    if (gm >= m) continue;
                    float v = acc[rt][ct][rr] + bv;
                    int bg = batch[gm];
                    if (bg == bp) { run += v; }
                    else {
                        if (bp >= 0) atomicAdd(&Cout[(size_t)bp * N + gn], run);
                        bp = bg; run = v;
                    }
                }
                if (bp >= 0) atomicAdd(&Cout[(size_t)bp * N + gn], run);
            } else {
#pragma unroll
                for (int rr = 0; rr < 4; ++rr) {
                    int gm = gm00 + rt * 16 + rr;
                    if (gm >= m) continue;
                    float v = acc[rt][ct][rr] + bv;
                    if (EPI == 0) {
                        Tout[pk_off(gm, gn, nKBo)] = f2h_bits(sp(v));
                    } else {
                        Tout[(size_t)gm * N + gn] = f2h_bits(v);  // raw h, f16
                        s += v;
                        ss += v * v;
                    }
                }
            }
        }
        if (EPI == 1) {
            s  += __shfl_xor(s, 16);  s  += __shfl_xor(s, 32);
            ss += __shfl_xor(ss, 16); ss += __shfl_xor(ss, 32);
            if (kq == 0) {
                atomicAdd(&bnsum[gn], s);
                atomicAdd(&bnsum[D_ + gn], ss);
            }
        }
    }
}

// ---------------------------------------------------------------------------
__global__ __launch_bounds__(256)
void count_kernel(const int* __restrict__ batch, float* __restrict__ cnt, int N)
{
    int i = blockIdx.x * 256 + threadIdx.x;
    if (i < N) atomicAdd(&cnt[batch[i]], 1.f);
}

__global__ __launch_bounds__(256)
void pool_div_kernel(float* __restrict__ gfeat, const float* __restrict__ cnt, int G)
{
    int g = blockIdx.x;
    float inv = 1.f / fmaxf(cnt[g], 1.f);
    for (int c = threadIdx.x; c < FD_; c += 256)
        gfeat[(size_t)g * FD_ + c] *= inv;
}

// ---------------------------------------------------------------------------
// fp32 GEMM for the small head: C = softplus(A @ W + bias)
// ---------------------------------------------------------------------------
#define BM 64
#define BN 64
#define BK 16

__global__ __launch_bounds__(256)
void gemm_head(const float* __restrict__ A, const float* __restrict__ W,
               const float* __restrict__ bias, float* __restrict__ C,
               int M, int N, int K)
{
    __shared__ float As[BK][BM + 4];
    __shared__ float Ws[BK][BN + 4];

    int tid = threadIdx.x;
    int bm = blockIdx.y * BM;
    int bn = blockIdx.x * BN;
    int tx = tid & 15;
    int ty = tid >> 4;

    float acc[4][4] = {};

    int a_m = tid >> 2;
    int a_k = (tid & 3) * 4;
    int w_k = tid >> 4;
    int w_n = (tid & 15) * 4;

    for (int k0 = 0; k0 < K; k0 += BK) {
        int gm = bm + a_m;
        float4 av = make_float4(0.f, 0.f, 0.f, 0.f);
        if (gm < M)
            av = *(const float4*)(A + (size_t)gm * K + k0 + a_k);
        As[a_k + 0][a_m] = av.x;
        As[a_k + 1][a_m] = av.y;
        As[a_k + 2][a_m] = av.z;
        As[a_k + 3][a_m] = av.w;

        float4 wv = *(const float4*)(W + (size_t)(k0 + w_k) * N + bn + w_n);
        *(float4*)&Ws[w_k][w_n] = wv;

        __syncthreads();

#pragma unroll
        for (int k = 0; k < BK; ++k) {
            float4 a4 = *(const float4*)&As[k][ty * 4];
            float4 b4 = *(const float4*)&Ws[k][tx * 4];
            float a[4] = {a4.x, a4.y, a4.z, a4.w};
            float b[4] = {b4.x, b4.y, b4.z, b4.w};
#pragma unroll
            for (int i = 0; i < 4; ++i)
#pragma unroll
                for (int j = 0; j < 4; ++j)
                    acc[i][j] += a[i] * b[j];
        }
        __syncthreads();
    }

#pragma unroll
    for (int i = 0; i < 4; ++i) {
        int gm = bm + ty * 4 + i;
        if (gm >= M) continue;
#pragma unroll
        for (int j = 0; j < 4; ++j) {
            int gn = bn + tx * 4 + j;
            C[(size_t)gm * N + gn] = sp(acc[i][j] + bias[gn]);
        }
    }
}

__global__ __launch_bounds__(256)
void head2_kernel(const float* __restrict__ hid, const float* __restrict__ w2,
                  const float* __restrict__ b2, float* __restrict__ out, int G)
{
    __shared__ float red[256];
    int g = blockIdx.x;
    int t = threadIdx.x;
    float v = hid[(size_t)g * 256 + t] * w2[t];
    red[t] = v;
    __syncthreads();
    for (int s = 128; s > 0; s >>= 1) {
        if (t < s) red[t] += red[t + s];
        __syncthreads();
    }
    if (t == 0) out[g] = red[0] + b2[0];
}

// ---------------------------------------------------------------------------
extern "C" void kernel_launch(void* const* d_in, const int* in_sizes, int n_in,
                              void* d_out, int out_size, void* d_ws, size_t ws_size,
                              hipStream_t stream)
{
    const int N = in_sizes[0];
    const int E = in_sizes[3];
    const int G = out_size;

    const int*   atomics  = (const int*)d_in[0];
    const float* pos      = (const float*)d_in[1];
    const int*   eidx     = (const int*)d_in[2];
    const int*   eattr    = (const int*)d_in[3];
    const int*   batch    = (const int*)d_in[4];
    const float* x_emb1   = (const float*)d_in[5];
    const float* x_emb2_w = (const float*)d_in[6];
    const float* x_emb2_b = (const float*)d_in[7];
    const float* edge_emb = (const float*)d_in[8];
    const float* mlp_w1   = (const float*)d_in[9];
    const float* mlp_b1   = (const float*)d_in[10];
    const float* mlp_w2   = (const float*)d_in[11];
    const float* mlp_b2   = (const float*)d_in[12];
    const float* bn_g     = (const float*)d_in[13];
    const float* bn_b     = (const float*)d_in[14];
    const float* feat_w   = (const float*)d_in[15];
    const float* feat_b   = (const float*)d_in[16];
    const float* head_w1  = (const float*)d_in[17];
    const float* head_b1  = (const float*)d_in[18];
    const float* head_w2  = (const float*)d_in[19];
    const float* head_b2  = (const float*)d_in[20];
    float* out = (float*)d_out;

    const int* src = eidx;
    const int* dst = eidx + E;

    char* ws = (char*)d_ws;
    size_t off = 0;
    auto carve = [&](size_t bytes) {
        void* p = ws + off;
        off += (bytes + 255) & ~(size_t)255;
        return p;
    };

    const int nRB = (N + 127) / 128;           // 128-row tiles

    // ---- fixed carve (~185 MB) ----
    ushort_t* h16  = (ushort_t*)carve((size_t)N * D_ * 2);             // 51.2 MB
    ushort_t* hact = (ushort_t*)carve((size_t)N * D_ * 2);             // 51.2 MB [R15]
    ushort_t* aggP = (ushort_t*)carve((size_t)nRB * 8 * TILE_SH * 2);  // 52.9 MB
    const size_t WTILES = 32 * TILE_SH;
    ushort_t* w1Ph = (ushort_t*)carve((size_t)L_ * WTILES * 2);
    ushort_t* w1Pl = (ushort_t*)carve((size_t)L_ * WTILES * 2);
    ushort_t* w2Ph = (ushort_t*)carve((size_t)L_ * WTILES * 2);
    ushort_t* w2Pl = (ushort_t*)carve((size_t)L_ * WTILES * 2);
    ushort_t* fPh  = (ushort_t*)carve(WTILES * 2);
    ushort_t* fPl  = (ushort_t*)carve(WTILES * 2);
    float* bnsum   = (float*)carve(2 * D_ * 4);
    float* gfeat   = (float*)carve((size_t)G * FD_ * 4);               // 8.2 MB
    float* cnt     = (float*)carve((size_t)G * 4);
    float* hid     = (float*)carve((size_t)G * (FD_ / 2) * 4);
    // CSR buffers (~5 MB)
    int* cnt_i   = (int*)carve((size_t)N * 4);
    int* start_i = (int*)carve((size_t)N * 4);
    int* cursor  = (int*)carve((size_t)N * 4);
    int* total   = (int*)carve(4);
    uint32_t* elist = (uint32_t*)carve((size_t)E * 4);

    // ---- adaptive chunk for packed f16 T (16 tiles x 8448 B per 128 rows) ----
    size_t avail = (ws_size > off + 4096) ? (ws_size - off - 4096) : 0;
    long long mcb = (long long)(avail / (16 * (size_t)TILE_SH * 2));
    if (mcb > nRB) mcb = nRB;
    if (mcb < 16) mcb = 16;                    // floor (ws proven >= this)
    const int Mc = (int)(mcb * 128);
    ushort_t* tP = (ushort_t*)carve((size_t)mcb * 16 * TILE_SH * 2);

    const float invN = 1.f / (float)N;

    // ---- CSR build (once per launch, reused all 5 layers) ----
    hipMemsetAsync(cnt_i, 0, (size_t)N * 4, stream);
    hipMemsetAsync(total, 0, 4, stream);
    hist_kernel<<<(E + 255) / 256, 256, 0, stream>>>(dst, cnt_i, E);
    alloc_kernel<<<(N + 255) / 256, 256, 0, stream>>>(cnt_i, start_i, cursor, total, N);
    fill_kernel<<<(E + 255) / 256, 256, 0, stream>>>(src, dst, eattr, cursor, elist, E);

    // ---- one-time weight packing (all split f16) ----
    for (int l = 0; l < L_; ++l) {
        convert_w_pack<<<dim3(8, 4), 256, 0, stream>>>(
            mlp_w1 + (size_t)l * D_ * FD_, w1Ph + (size_t)l * WTILES,
            w1Pl + (size_t)l * WTILES, FD_, 8);
        convert_w_pack<<<dim3(16, 2), 256, 0, stream>>>(
            mlp_w2 + (size_t)l * FD_ * D_, w2Ph + (size_t)l * WTILES,
            w2Pl + (size_t)l * WTILES, D_, 16);
    }
    convert_w_pack<<<dim3(8, 4), 256, 0, stream>>>(feat_w, fPh, fPl, FD_, 8);

    init_h_kernel<<<N, 256, 0, stream>>>(atomics, pos, x_emb1, x_emb2_w, x_emb2_b, h16, N);

    const long long total8 = (long long)N * D_ / 8;
    const int ACTB = (int)((total8 + 255) / 256);
    const int GB4 = (N + 3) / 4;

    for (int l = 0; l < L_; ++l) {
        const float* ee_l = edge_emb + (size_t)l * 2 * D_;
        // activation once per node (identity for l=0: read h16 directly)
        const ushort_t* gsrc = h16;
        if (l > 0) {
            act16_kernel<<<ACTB, 256, 0, stream>>>(h16, hact, bnsum,
                bn_g + (size_t)(l - 1) * D_, bn_b + (size_t)(l - 1) * D_, total8, invN);
            gsrc = hact;
        }
        gather_pack4_kernel<<<GB4, 256, 0, stream>>>(gsrc, elist, start_i, cnt_i,
                                                     ee_l, aggP, N);

        hipMemsetAsync(bnsum, 0, 2 * D_ * 4, stream);
        for (int r0 = 0; r0 < N; r0 += Mc) {
            int m = min(Mc, N - r0);
            int mb = (m + 127) / 128;
            // T = sp(agg @ W1 + b1)  -> packed f16
            gemm_p16<0><<<dim3(4, mb), 256, 0, stream>>>(
                aggP + (size_t)(r0 >> 7) * 8 * TILE_SH,
                w1Ph + (size_t)l * WTILES, w1Pl + (size_t)l * WTILES,
                mlp_b1 + (size_t)l * FD_, tP, nullptr, nullptr, nullptr,
                m, FD_, 8);
            // h16 = f16(T @ W2 + b2) raw + bn stats
            gemm_p16<1><<<dim3(2, mb), 256, 0, stream>>>(
                tP, w2Ph + (size_t)l * WTILES, w2Pl + (size_t)l * WTILES,
                mlp_b2 + (size_t)l * D_, h16 + (size_t)r0 * D_, nullptr, bnsum, nullptr,
                m, D_, 16);
        }
    }

    // ---- feat + mean-pool: BN(h16) -> packed f16 (reuse aggP), pooled gemm ----
    bn_pack_kernel<<<N, 256, 0, stream>>>(h16, bnsum, bn_g + (size_t)(L_ - 1) * D_,
                                          bn_b + (size_t)(L_ - 1) * D_, aggP, N, invN);
    hipMemsetAsync(gfeat, 0, (size_t)G * FD_ * 4, stream);
    hipMemsetAsync(cnt, 0, (size_t)G * 4, stream);
    gemm_p16<2><<<dim3(4, nRB), 256, 0, stream>>>(
        aggP, fPh, fPl, feat_b, nullptr, gfeat, nullptr, batch, N, FD_, 8);
    count_kernel<<<(N + 255) / 256, 256, 0, stream>>>(batch, cnt, N);
    pool_div_kernel<<<G, 256, 0, stream>>>(gfeat, cnt, G);

    // ---- head ----
    gemm_head<<<dim3((FD_ / 2) / BN, (G + BM - 1) / BM), 256, 0, stream>>>(
        gfeat, head_w1, head_b1, hid, G, FD_ / 2, FD_);
    head2_kernel<<<G, 256, 0, stream>>>(hid, head_w2, head_b2, out, G);
}

// Round 16
// 2075.635 us; speedup vs baseline: 1.1986x; 1.0612x over previous
//
#include <hip/hip_runtime.h>
#include <hip/hip_bf16.h>
#include <hip/hip_fp16.h>
#include <stdint.h>

#define D_  256   // emb dim
#define FD_ 512   // feat dim
#define L_  5     // layers
#define EPS_ 1e-5f

// packed-tile format (R6-proven): tile = 128 rows x 32 k, stored as 4 k-planes
// (8 k each): plane = 128 rows x 16B + 64B pad = 2112B. tile = 8448B = 4224 sh.
#define PLANE_SH 1056
#define TILE_SH  4224

typedef unsigned short ushort_t;
typedef __attribute__((ext_vector_type(8))) _Float16 h8v;  // 8 f16 (MFMA frag)
typedef __attribute__((ext_vector_type(4))) float    f4v;  // MFMA C/D frag

// numerically-stable softplus == jnp.logaddexp(x, 0) — NATIVE exp/log (R11-proven)
__device__ __forceinline__ float sp(float x) {
    float t = __expf(-fabsf(x));            // native v_exp_f32
    return fmaxf(x, 0.f) + __logf(1.f + t); // native v_log_f32
}

__device__ __forceinline__ ushort_t f2h_bits(float v) {
    union { _Float16 h; ushort_t u; } c;
    c.h = (_Float16)v;
    return c.u;
}

__device__ __forceinline__ float h2f(ushort_t u) {
    union { ushort_t u; _Float16 h; } c;
    c.u = u;
    return (float)c.h;
}

// async global->LDS: lds dest = wave-uniform base + lane*16B
__device__ __forceinline__ void gload_lds16(const void* g, void* l) {
    __builtin_amdgcn_global_load_lds((const __attribute__((address_space(1))) void*)g,
                                     (__attribute__((address_space(3))) void*)l,
                                     16, 0, 0);
}

// packed-f16 element offset for (row gm, col gn) with nKB = cols/32
__device__ __forceinline__ size_t pk_off(int gm, int gn, int nKB) {
    return ((size_t)(gm >> 7) * nKB + (gn >> 5)) * TILE_SH
         + (size_t)((gn >> 3) & 3) * PLANE_SH
         + (gm & 127) * 8 + (gn & 7);
}

// ---------------------------------------------------------------------------
// h16[i,d] = f16( x_emb1[atomics[i],d] + pos[i,:] @ x_emb2_w[:,d] + x_emb2_b[d] )
// ---------------------------------------------------------------------------
__global__ __launch_bounds__(256)
void init_h_kernel(const int* __restrict__ atomics, const float* __restrict__ pos,
                   const float* __restrict__ emb1, const float* __restrict__ w2,
                   const float* __restrict__ b2, ushort_t* __restrict__ h16, int N)
{
    int i = blockIdx.x;
    int d = threadIdx.x;
    int a = atomics[i];
    float p0 = pos[(size_t)i * 3 + 0];
    float p1 = pos[(size_t)i * 3 + 1];
    float p2 = pos[(size_t)i * 3 + 2];
    float v = emb1[(size_t)a * D_ + d]
            + p0 * w2[0 * D_ + d]
            + p1 * w2[1 * D_ + d]
            + p2 * w2[2 * D_ + d]
            + b2[d];
    h16[(size_t)i * D_ + d] = f2h_bits(v);
}

// ---------------------------------------------------------------------------
// CSR build (unordered segments; segment order irrelevant)
// ---------------------------------------------------------------------------
__global__ __launch_bounds__(256)
void hist_kernel(const int* __restrict__ dst, int* __restrict__ cnt, int E)
{
    int e = blockIdx.x * 256 + threadIdx.x;
    if (e < E) atomicAdd(&cnt[dst[e]], 1);
}

__global__ __launch_bounds__(256)
void alloc_kernel(const int* __restrict__ cnt, int* __restrict__ start,
                  int* __restrict__ cursor, int* __restrict__ total, int N)
{
    int i = blockIdx.x * 256 + threadIdx.x;
    if (i < N) {
        int s = atomicAdd(total, cnt[i]);
        start[i] = s;
        cursor[i] = s;
    }
}

__global__ __launch_bounds__(256)
void fill_kernel(const int* __restrict__ src, const int* __restrict__ dst,
                 const int* __restrict__ attr, int* __restrict__ cursor,
                 uint32_t* __restrict__ elist, int E)
{
    int e = blockIdx.x * 256 + threadIdx.x;
    if (e < E) {
        int p = atomicAdd(&cursor[dst[e]], 1);
        elist[p] = (uint32_t)src[e] | ((uint32_t)attr[e] << 30);
    }
}

// ---------------------------------------------------------------------------
// act16 (R15-proven): hact = f16( sp( BN-affine(h16) ) ), 8 ch/thread
// ---------------------------------------------------------------------------
__global__ __launch_bounds__(256)
void act16_kernel(const ushort_t* __restrict__ h16, ushort_t* __restrict__ hact,
                  const float* __restrict__ bnsum, const float* __restrict__ gamma,
                  const float* __restrict__ beta, long long total8, float invN)
{
    __shared__ float ssc[256], ssh[256];
    int t = threadIdx.x;
    {
        float mean = bnsum[t] * invN;
        float var = bnsum[D_ + t] * invN - mean * mean;
        float sc = gamma[t] * rsqrtf(fmaxf(var, 0.f) + EPS_);
        ssc[t] = sc;
        ssh[t] = beta[t] - mean * sc;
    }
    __syncthreads();
    long long idx = (long long)blockIdx.x * 256 + t;
    if (idx >= total8) return;
    int c0 = (int)((idx * 8) & 255);
    uint4 in = *(const uint4*)(h16 + idx * 8);
    ushort_t* ip = (ushort_t*)&in;
    ushort_t ov[8];
#pragma unroll
    for (int j = 0; j < 8; ++j)
        ov[j] = f2h_bits(sp(h2f(ip[j]) * ssc[c0 + j] + ssh[c0 + j]));
    *(uint4*)(hact + idx * 8) = *(uint4*)ov;
}

// ---------------------------------------------------------------------------
// gather_pack4 (R15-proven): 4 rows per block, pure sum, full-line packed writes
// ---------------------------------------------------------------------------
__global__ __launch_bounds__(256)
void gather_pack4_kernel(const ushort_t* __restrict__ hact, const uint32_t* __restrict__ elist,
                         const int* __restrict__ start, const int* __restrict__ cnt,
                         const float* __restrict__ ee_l, ushort_t* __restrict__ aggP, int N)
{
    int i0 = blockIdx.x * 4;
    int d = threadIdx.x;
    float ee0 = ee_l[d];        // bond 0
    float ee1 = ee_l[D_ + d];   // bond 1 (also self-loop)
    float acc[4];
#pragma unroll
    for (int r = 0; r < 4; ++r) {
        int i = i0 + r;
        if (i >= N) { acc[r] = 0.f; continue; }
        float a = h2f(hact[(size_t)i * D_ + d]) + ee1;
        int base = start[i], deg = cnt[i];
        for (int j = 0; j < deg; ++j) {
            uint32_t p = elist[base + j];
            int s = p & 0x3FFFFFFF;
            a += h2f(hact[(size_t)s * D_ + d]) + ((p >> 30) ? ee1 : ee0);
        }
        acc[r] = a;
    }
#pragma unroll
    for (int r = 0; r < 4; ++r) {
        int i = i0 + r;
        if (i < N) aggP[pk_off(i, d, 8)] = f2h_bits(acc[r]);
    }
}

// bn_pack: BN affine (no softplus) of last layer -> packed f16 (feeds feat gemm)
__global__ __launch_bounds__(256)
void bn_pack_kernel(const ushort_t* __restrict__ h16, const float* __restrict__ bnsum,
                    const float* __restrict__ gamma, const float* __restrict__ beta,
                    ushort_t* __restrict__ outP, int N, float invN)
{
    int i = blockIdx.x;
    int d = threadIdx.x;
    float mean = bnsum[d] * invN;
    float var = bnsum[D_ + d] * invN - mean * mean;
    float inv = 1.f / sqrtf(fmaxf(var, 0.f) + EPS_);
    float v = (h2f(h16[(size_t)i * D_ + d]) - mean) * inv * gamma[d] + beta[d];
    outP[pk_off(i, d, 8)] = f2h_bits(v);
}

// ---------------------------------------------------------------------------
// weight pack [R16]: W fp32 [K][N] -> SINGLE f16 tiles (nb, kb), row = col n
// ---------------------------------------------------------------------------
__global__ __launch_bounds__(256)
void convert_w_pack(const float* __restrict__ W, ushort_t* __restrict__ dh,
                    int N, int nKB)
{
    int kb = blockIdx.x, nb = blockIdx.y;
    int n = threadIdx.x >> 1, half = threadIdx.x & 1;
#pragma unroll
    for (int j = 0; j < 2; ++j) {
        int kq = half * 2 + j;
        size_t o = (size_t)(nb * nKB + kb) * TILE_SH + kq * PLANE_SH + n * 8;
#pragma unroll
        for (int jj = 0; jj < 8; ++jj) {
            float w = W[(size_t)(kb * 32 + kq * 8 + jj) * N + nb * 128 + n];
            dh[o + jj] = f2h_bits(w);
        }
    }
}

// ---------------------------------------------------------------------------
// gemm_p16<EPI> [R16]: SINGLE-f16 A and B, 1 MFMA per (rt,ct) — half the MFMA
// work and staging of R15's split-B. 2 K-tiles per barrier round (R13-proven).
//   EPI 0: softplus -> packed f16 Tout (nKBo = N/32)
//   EPI 1: f16 row-major Tout[m][N] (raw h) + fused bn partial sums (N == 256)
//   EPI 2: run-merged atomicAdd into Cout[batch[gm]*N + gn]  (graph pool)
// grid (N/128, mb); block 256 thr / 4 waves (2x2 of 64x64); tile 128x128.
// LDS 33.8 KB -> 4 blocks/CU.
// ---------------------------------------------------------------------------
template <int EPI>
__global__ __launch_bounds__(256)
void gemm_p16(const ushort_t* __restrict__ APK, const ushort_t* __restrict__ BPK,
              const float* __restrict__ bias,
              ushort_t* __restrict__ Tout, float* __restrict__ Cout,
              float* __restrict__ bnsum, const int* __restrict__ batch,
              int m, int N, int nKB)
{
    __shared__ ushort_t lA[2 * TILE_SH], lB[2 * TILE_SH];   // 33.8 KB

    int tid = threadIdx.x, wave = tid >> 6, lane = tid & 63;
    int nb = blockIdx.x, rb = blockIdx.y;
    int wr = wave >> 1, wc = wave & 1;
    int fr = lane & 15, kq = lane >> 4;

    f4v acc[4][4];
#pragma unroll
    for (int i = 0; i < 4; ++i)
#pragma unroll
        for (int j = 0; j < 4; ++j)
            acc[i][j] = (f4v){0.f, 0.f, 0.f, 0.f};

    for (int kb = 0; kb < nKB; kb += 2) {
        const ushort_t* as = APK + (size_t)(rb * nKB + kb) * TILE_SH;
        const ushort_t* bs = BPK + (size_t)(nb * nKB + kb) * TILE_SH;
        for (int c = tid; c < 1056; c += 256) {
            int base = (c - lane) * 8;   // wave-uniform LDS base
            gload_lds16(as + c * 8, lA + base);
            gload_lds16(bs + c * 8, lB + base);
        }
        __syncthreads();

#pragma unroll
        for (int sub = 0; sub < 2; ++sub) {
            const ushort_t* sA = lA + sub * TILE_SH;
            const ushort_t* sB = lB + sub * TILE_SH;
            h8v Af[4], Bf[4];
#pragma unroll
            for (int t = 0; t < 4; ++t) {
                int ao = kq * PLANE_SH + (wr * 64 + fr + t * 16) * 8;
                int bo = kq * PLANE_SH + (wc * 64 + fr + t * 16) * 8;
                Af[t] = *(const h8v*)(sA + ao);
                Bf[t] = *(const h8v*)(sB + bo);
            }
#pragma unroll
            for (int rt = 0; rt < 4; ++rt)
#pragma unroll
                for (int ct = 0; ct < 4; ++ct)
                    acc[rt][ct] = __builtin_amdgcn_mfma_f32_16x16x32_f16(Af[rt], Bf[ct], acc[rt][ct], 0, 0, 0);
        }
        __syncthreads();
    }

    // epilogue: C/D layout col = lane&15, row = (lane>>4)*4 + reg
    int gm00 = rb * 128 + wr * 64 + kq * 4;
    int gn0  = nb * 128 + wc * 64 + fr;
    int nKBo = N >> 5;
#pragma unroll
    for (int ct = 0; ct < 4; ++ct) {
        int gn = gn0 + ct * 16;
        float bv = bias[gn];
        float s = 0.f, ss = 0.f;
#pragma unroll
        for (int rt = 0; rt < 4; ++rt) {
            if (EPI == 2) {
                int bp = -1; float run = 0.f;
#pragma unroll
                for (int rr = 0; rr < 4; ++rr) {
                    int gm = gm00 + rt * 16 + rr;
                    if (gm >= m) continue;
                    float v = acc[rt][ct][rr] + bv;
                    int bg = batch[gm];
                    if (bg == bp) { run += v; }
                    else {
                        if (bp >= 0) atomicAdd(&Cout[(size_t)bp * N + gn], run);
                        bp = bg; run = v;
                    }
                }
                if (bp >= 0) atomicAdd(&Cout[(size_t)bp * N + gn], run);
            } else {
#pragma unroll
                for (int rr = 0; rr < 4; ++rr) {
                    int gm = gm00 + rt * 16 + rr;
                    if (gm >= m) continue;
                    float v = acc[rt][ct][rr] + bv;
                    if (EPI == 0) {
                        Tout[pk_off(gm, gn, nKBo)] = f2h_bits(sp(v));
                    } else {
                        Tout[(size_t)gm * N + gn] = f2h_bits(v);  // raw h, f16
                        s += v;
                        ss += v * v;
                    }
                }
            }
        }
        if (EPI == 1) {
            s  += __shfl_xor(s, 16);  s  += __shfl_xor(s, 32);
            ss += __shfl_xor(ss, 16); ss += __shfl_xor(ss, 32);
            if (kq == 0) {
                atomicAdd(&bnsum[gn], s);
                atomicAdd(&bnsum[D_ + gn], ss);
            }
        }
    }
}

// ---------------------------------------------------------------------------
__global__ __launch_bounds__(256)
void count_kernel(const int* __restrict__ batch, float* __restrict__ cnt, int N)
{
    int i = blockIdx.x * 256 + threadIdx.x;
    if (i < N) atomicAdd(&cnt[batch[i]], 1.f);
}

__global__ __launch_bounds__(256)
void pool_div_kernel(float* __restrict__ gfeat, const float* __restrict__ cnt, int G)
{
    int g = blockIdx.x;
    float inv = 1.f / fmaxf(cnt[g], 1.f);
    for (int c = threadIdx.x; c < FD_; c += 256)
        gfeat[(size_t)g * FD_ + c] *= inv;
}

// ---------------------------------------------------------------------------
// fp32 GEMM for the small head: C = softplus(A @ W + bias)
// ---------------------------------------------------------------------------
#define BM 64
#define BN 64
#define BK 16

__global__ __launch_bounds__(256)
void gemm_head(const float* __restrict__ A, const float* __restrict__ W,
               const float* __restrict__ bias, float* __restrict__ C,
               int M, int N, int K)
{
    __shared__ float As[BK][BM + 4];
    __shared__ float Ws[BK][BN + 4];

    int tid = threadIdx.x;
    int bm = blockIdx.y * BM;
    int bn = blockIdx.x * BN;
    int tx = tid & 15;
    int ty = tid >> 4;

    float acc[4][4] = {};

    int a_m = tid >> 2;
    int a_k = (tid & 3) * 4;
    int w_k = tid >> 4;
    int w_n = (tid & 15) * 4;

    for (int k0 = 0; k0 < K; k0 += BK) {
        int gm = bm + a_m;
        float4 av = make_float4(0.f, 0.f, 0.f, 0.f);
        if (gm < M)
            av = *(const float4*)(A + (size_t)gm * K + k0 + a_k);
        As[a_k + 0][a_m] = av.x;
        As[a_k + 1][a_m] = av.y;
        As[a_k + 2][a_m] = av.z;
        As[a_k + 3][a_m] = av.w;

        float4 wv = *(const float4*)(W + (size_t)(k0 + w_k) * N + bn + w_n);
        *(float4*)&Ws[w_k][w_n] = wv;

        __syncthreads();

#pragma unroll
        for (int k = 0; k < BK; ++k) {
            float4 a4 = *(const float4*)&As[k][ty * 4];
            float4 b4 = *(const float4*)&Ws[k][tx * 4];
            float a[4] = {a4.x, a4.y, a4.z, a4.w};
            float b[4] = {b4.x, b4.y, b4.z, b4.w};
#pragma unroll
            for (int i = 0; i < 4; ++i)
#pragma unroll
                for (int j = 0; j < 4; ++j)
                    acc[i][j] += a[i] * b[j];
        }
        __syncthreads();
    }

#pragma unroll
    for (int i = 0; i < 4; ++i) {
        int gm = bm + ty * 4 + i;
        if (gm >= M) continue;
#pragma unroll
        for (int j = 0; j < 4; ++j) {
            int gn = bn + tx * 4 + j;
            C[(size_t)gm * N + gn] = sp(acc[i][j] + bias[gn]);
        }
    }
}

__global__ __launch_bounds__(256)
void head2_kernel(const float* __restrict__ hid, const float* __restrict__ w2,
                  const float* __restrict__ b2, float* __restrict__ out, int G)
{
    __shared__ float red[256];
    int g = blockIdx.x;
    int t = threadIdx.x;
    float v = hid[(size_t)g * 256 + t] * w2[t];
    red[t] = v;
    __syncthreads();
    for (int s = 128; s > 0; s >>= 1) {
        if (t < s) red[t] += red[t + s];
        __syncthreads();
    }
    if (t == 0) out[g] = red[0] + b2[0];
}

// ---------------------------------------------------------------------------
extern "C" void kernel_launch(void* const* d_in, const int* in_sizes, int n_in,
                              void* d_out, int out_size, void* d_ws, size_t ws_size,
                              hipStream_t stream)
{
    const int N = in_sizes[0];
    const int E = in_sizes[3];
    const int G = out_size;

    const int*   atomics  = (const int*)d_in[0];
    const float* pos      = (const float*)d_in[1];
    const int*   eidx     = (const int*)d_in[2];
    const int*   eattr    = (const int*)d_in[3];
    const int*   batch    = (const int*)d_in[4];
    const float* x_emb1   = (const float*)d_in[5];
    const float* x_emb2_w = (const float*)d_in[6];
    const float* x_emb2_b = (const float*)d_in[7];
    const float* edge_emb = (const float*)d_in[8];
    const float* mlp_w1   = (const float*)d_in[9];
    const float* mlp_b1   = (const float*)d_in[10];
    const float* mlp_w2   = (const float*)d_in[11];
    const float* mlp_b2   = (const float*)d_in[12];
    const float* bn_g     = (const float*)d_in[13];
    const float* bn_b     = (const float*)d_in[14];
    const float* feat_w   = (const float*)d_in[15];
    const float* feat_b   = (const float*)d_in[16];
    const float* head_w1  = (const float*)d_in[17];
    const float* head_b1  = (const float*)d_in[18];
    const float* head_w2  = (const float*)d_in[19];
    const float* head_b2  = (const float*)d_in[20];
    float* out = (float*)d_out;

    const int* src = eidx;
    const int* dst = eidx + E;

    char* ws = (char*)d_ws;
    size_t off = 0;
    auto carve = [&](size_t bytes) {
        void* p = ws + off;
        off += (bytes + 255) & ~(size_t)255;
        return p;
    };

    const int nRB = (N + 127) / 128;           // 128-row tiles

    // ---- fixed carve (~175 MB) ----
    ushort_t* h16  = (ushort_t*)carve((size_t)N * D_ * 2);             // 51.2 MB
    ushort_t* hact = (ushort_t*)carve((size_t)N * D_ * 2);             // 51.2 MB
    ushort_t* aggP = (ushort_t*)carve((size_t)nRB * 8 * TILE_SH * 2);  // 52.9 MB
    const size_t WTILES = 32 * TILE_SH;
    ushort_t* w1P = (ushort_t*)carve((size_t)L_ * WTILES * 2);         // single f16 [R16]
    ushort_t* w2P = (ushort_t*)carve((size_t)L_ * WTILES * 2);
    ushort_t* fP  = (ushort_t*)carve(WTILES * 2);
    float* bnsum  = (float*)carve(2 * D_ * 4);
    float* gfeat  = (float*)carve((size_t)G * FD_ * 4);                // 8.2 MB
    float* cnt    = (float*)carve((size_t)G * 4);
    float* hid    = (float*)carve((size_t)G * (FD_ / 2) * 4);
    // CSR buffers (~5 MB)
    int* cnt_i   = (int*)carve((size_t)N * 4);
    int* start_i = (int*)carve((size_t)N * 4);
    int* cursor  = (int*)carve((size_t)N * 4);
    int* total   = (int*)carve(4);
    uint32_t* elist = (uint32_t*)carve((size_t)E * 4);

    // ---- adaptive chunk for packed f16 T (16 tiles x 8448 B per 128 rows) ----
    size_t avail = (ws_size > off + 4096) ? (ws_size - off - 4096) : 0;
    long long mcb = (long long)(avail / (16 * (size_t)TILE_SH * 2));
    if (mcb > nRB) mcb = nRB;
    if (mcb < 16) mcb = 16;                    // floor (ws proven >= this)
    const int Mc = (int)(mcb * 128);
    ushort_t* tP = (ushort_t*)carve((size_t)mcb * 16 * TILE_SH * 2);

    const float invN = 1.f / (float)N;

    // ---- CSR build (once per launch, reused all 5 layers) ----
    hipMemsetAsync(cnt_i, 0, (size_t)N * 4, stream);
    hipMemsetAsync(total, 0, 4, stream);
    hist_kernel<<<(E + 255) / 256, 256, 0, stream>>>(dst, cnt_i, E);
    alloc_kernel<<<(N + 255) / 256, 256, 0, stream>>>(cnt_i, start_i, cursor, total, N);
    fill_kernel<<<(E + 255) / 256, 256, 0, stream>>>(src, dst, eattr, cursor, elist, E);

    // ---- one-time weight packing (single f16) ----
    for (int l = 0; l < L_; ++l) {
        convert_w_pack<<<dim3(8, 4), 256, 0, stream>>>(
            mlp_w1 + (size_t)l * D_ * FD_, w1P + (size_t)l * WTILES, FD_, 8);
        convert_w_pack<<<dim3(16, 2), 256, 0, stream>>>(
            mlp_w2 + (size_t)l * FD_ * D_, w2P + (size_t)l * WTILES, D_, 16);
    }
    convert_w_pack<<<dim3(8, 4), 256, 0, stream>>>(feat_w, fP, FD_, 8);

    init_h_kernel<<<N, 256, 0, stream>>>(atomics, pos, x_emb1, x_emb2_w, x_emb2_b, h16, N);

    const long long total8 = (long long)N * D_ / 8;
    const int ACTB = (int)((total8 + 255) / 256);
    const int GB4 = (N + 3) / 4;

    for (int l = 0; l < L_; ++l) {
        const float* ee_l = edge_emb + (size_t)l * 2 * D_;
        // activation once per node (identity for l=0: read h16 directly)
        const ushort_t* gsrc = h16;
        if (l > 0) {
            act16_kernel<<<ACTB, 256, 0, stream>>>(h16, hact, bnsum,
                bn_g + (size_t)(l - 1) * D_, bn_b + (size_t)(l - 1) * D_, total8, invN);
            gsrc = hact;
        }
        gather_pack4_kernel<<<GB4, 256, 0, stream>>>(gsrc, elist, start_i, cnt_i,
                                                     ee_l, aggP, N);

        hipMemsetAsync(bnsum, 0, 2 * D_ * 4, stream);
        for (int r0 = 0; r0 < N; r0 += Mc) {
            int m = min(Mc, N - r0);
            int mb = (m + 127) / 128;
            // T = sp(agg @ W1 + b1)  -> packed f16
            gemm_p16<0><<<dim3(4, mb), 256, 0, stream>>>(
                aggP + (size_t)(r0 >> 7) * 8 * TILE_SH,
                w1P + (size_t)l * WTILES,
                mlp_b1 + (size_t)l * FD_, tP, nullptr, nullptr, nullptr,
                m, FD_, 8);
            // h16 = f16(T @ W2 + b2) raw + bn stats
            gemm_p16<1><<<dim3(2, mb), 256, 0, stream>>>(
                tP, w2P + (size_t)l * WTILES,
                mlp_b2 + (size_t)l * D_, h16 + (size_t)r0 * D_, nullptr, bnsum, nullptr,
                m, D_, 16);
        }
    }

    // ---- feat + mean-pool: BN(h16) -> packed f16 (reuse aggP), pooled gemm ----
    bn_pack_kernel<<<N, 256, 0, stream>>>(h16, bnsum, bn_g + (size_t)(L_ - 1) * D_,
                                          bn_b + (size_t)(L_ - 1) * D_, aggP, N, invN);
    hipMemsetAsync(gfeat, 0, (size_t)G * FD_ * 4, stream);
    hipMemsetAsync(cnt, 0, (size_t)G * 4, stream);
    gemm_p16<2><<<dim3(4, nRB), 256, 0, stream>>>(
        aggP, fP, feat_b, nullptr, gfeat, nullptr, batch, N, FD_, 8);
    count_kernel<<<(N + 255) / 256, 256, 0, stream>>>(batch, cnt, N);
    pool_div_kernel<<<G, 256, 0, stream>>>(gfeat, cnt, G);

    // ---- head ----
    gemm_head<<<dim3((FD_ / 2) / BN, (G + BM - 1) / BM), 256, 0, stream>>>(
        gfeat, head_w1, head_b1, hid, G, FD_ / 2, FD_);
    head2_kernel<<<G, 256, 0, stream>>>(hid, head_w2, head_b2, out, G);
}

// Round 17
// 2018.108 us; speedup vs baseline: 1.2328x; 1.0285x over previous
//
#include <hip/hip_runtime.h>
#include <hip/hip_bf16.h>
#include <hip/hip_fp16.h>
#include <stdint.h>

#define D_  256   // emb dim
#define FD_ 512   // feat dim
#define L_  5     // layers
#define EPS_ 1e-5f

// packed-tile format (R6-proven): tile = 128 rows x 32 k, stored as 4 k-planes
// (8 k each): plane = 128 rows x 16B + 64B pad = 2112B. tile = 8448B = 4224 sh.
#define PLANE_SH 1056
#define TILE_SH  4224

typedef unsigned short ushort_t;
typedef __attribute__((ext_vector_type(8))) _Float16 h8v;  // 8 f16 (MFMA frag)
typedef __attribute__((ext_vector_type(4))) float    f4v;  // MFMA C/D frag

// numerically-stable softplus == jnp.logaddexp(x, 0) — NATIVE exp/log (R11-proven)
__device__ __forceinline__ float sp(float x) {
    float t = __expf(-fabsf(x));            // native v_exp_f32
    return fmaxf(x, 0.f) + __logf(1.f + t); // native v_log_f32
}

__device__ __forceinline__ ushort_t f2h_bits(float v) {
    union { _Float16 h; ushort_t u; } c;
    c.h = (_Float16)v;
    return c.u;
}

__device__ __forceinline__ float h2f(ushort_t u) {
    union { ushort_t u; _Float16 h; } c;
    c.u = u;
    return (float)c.h;
}

// async global->LDS: lds dest = wave-uniform base + lane*16B
__device__ __forceinline__ void gload_lds16(const void* g, void* l) {
    __builtin_amdgcn_global_load_lds((const __attribute__((address_space(1))) void*)g,
                                     (__attribute__((address_space(3))) void*)l,
                                     16, 0, 0);
}

// packed-f16 element offset for (row gm, col gn) with nKB = cols/32
__device__ __forceinline__ size_t pk_off(int gm, int gn, int nKB) {
    return ((size_t)(gm >> 7) * nKB + (gn >> 5)) * TILE_SH
         + (size_t)((gn >> 3) & 3) * PLANE_SH
         + (gm & 127) * 8 + (gn & 7);
}

// ---------------------------------------------------------------------------
// h16[i,d] = f16( x_emb1[atomics[i],d] + pos[i,:] @ x_emb2_w[:,d] + x_emb2_b[d] )
// ---------------------------------------------------------------------------
__global__ __launch_bounds__(256)
void init_h_kernel(const int* __restrict__ atomics, const float* __restrict__ pos,
                   const float* __restrict__ emb1, const float* __restrict__ w2,
                   const float* __restrict__ b2, ushort_t* __restrict__ h16, int N)
{
    int i = blockIdx.x;
    int d = threadIdx.x;
    int a = atomics[i];
    float p0 = pos[(size_t)i * 3 + 0];
    float p1 = pos[(size_t)i * 3 + 1];
    float p2 = pos[(size_t)i * 3 + 2];
    float v = emb1[(size_t)a * D_ + d]
            + p0 * w2[0 * D_ + d]
            + p1 * w2[1 * D_ + d]
            + p2 * w2[2 * D_ + d]
            + b2[d];
    h16[(size_t)i * D_ + d] = f2h_bits(v);
}

// ---------------------------------------------------------------------------
// CSR build (unordered segments; segment order irrelevant)
// ---------------------------------------------------------------------------
__global__ __launch_bounds__(256)
void hist_kernel(const int* __restrict__ dst, int* __restrict__ cnt, int E)
{
    int e = blockIdx.x * 256 + threadIdx.x;
    if (e < E) atomicAdd(&cnt[dst[e]], 1);
}

__global__ __launch_bounds__(256)
void alloc_kernel(const int* __restrict__ cnt, int* __restrict__ start,
                  int* __restrict__ cursor, int* __restrict__ total, int N)
{
    int i = blockIdx.x * 256 + threadIdx.x;
    if (i < N) {
        int s = atomicAdd(total, cnt[i]);
        start[i] = s;
        cursor[i] = s;
    }
}

__global__ __launch_bounds__(256)
void fill_kernel(const int* __restrict__ src, const int* __restrict__ dst,
                 const int* __restrict__ attr, int* __restrict__ cursor,
                 uint32_t* __restrict__ elist, int E)
{
    int e = blockIdx.x * 256 + threadIdx.x;
    if (e < E) {
        int p = atomicAdd(&cursor[dst[e]], 1);
        elist[p] = (uint32_t)src[e] | ((uint32_t)attr[e] << 30);
    }
}

// ---------------------------------------------------------------------------
// act16 (R15-proven): hact = f16( sp( BN-affine(h16) ) ), 8 ch/thread
// ---------------------------------------------------------------------------
__global__ __launch_bounds__(256)
void act16_kernel(const ushort_t* __restrict__ h16, ushort_t* __restrict__ hact,
                  const float* __restrict__ bnsum, const float* __restrict__ gamma,
                  const float* __restrict__ beta, long long total8, float invN)
{
    __shared__ float ssc[256], ssh[256];
    int t = threadIdx.x;
    {
        float mean = bnsum[t] * invN;
        float var = bnsum[D_ + t] * invN - mean * mean;
        float sc = gamma[t] * rsqrtf(fmaxf(var, 0.f) + EPS_);
        ssc[t] = sc;
        ssh[t] = beta[t] - mean * sc;
    }
    __syncthreads();
    long long idx = (long long)blockIdx.x * 256 + t;
    if (idx >= total8) return;
    int c0 = (int)((idx * 8) & 255);
    uint4 in = *(const uint4*)(h16 + idx * 8);
    ushort_t* ip = (ushort_t*)&in;
    ushort_t ov[8];
#pragma unroll
    for (int j = 0; j < 8; ++j)
        ov[j] = f2h_bits(sp(h2f(ip[j]) * ssc[c0 + j] + ssh[c0 + j]));
    *(uint4*)(hact + idx * 8) = *(uint4*)ov;
}

// ---------------------------------------------------------------------------
// gather_pack4 (R15-proven): 4 rows per block, pure sum, full-line packed writes
// ---------------------------------------------------------------------------
__global__ __launch_bounds__(256)
void gather_pack4_kernel(const ushort_t* __restrict__ hact, const uint32_t* __restrict__ elist,
                         const int* __restrict__ start, const int* __restrict__ cnt,
                         const float* __restrict__ ee_l, ushort_t* __restrict__ aggP, int N)
{
    int i0 = blockIdx.x * 4;
    int d = threadIdx.x;
    float ee0 = ee_l[d];        // bond 0
    float ee1 = ee_l[D_ + d];   // bond 1 (also self-loop)
    float acc[4];
#pragma unroll
    for (int r = 0; r < 4; ++r) {
        int i = i0 + r;
        if (i >= N) { acc[r] = 0.f; continue; }
        float a = h2f(hact[(size_t)i * D_ + d]) + ee1;
        int base = start[i], deg = cnt[i];
        for (int j = 0; j < deg; ++j) {
            uint32_t p = elist[base + j];
            int s = p & 0x3FFFFFFF;
            a += h2f(hact[(size_t)s * D_ + d]) + ((p >> 30) ? ee1 : ee0);
        }
        acc[r] = a;
    }
#pragma unroll
    for (int r = 0; r < 4; ++r) {
        int i = i0 + r;
        if (i < N) aggP[pk_off(i, d, 8)] = f2h_bits(acc[r]);
    }
}

// bn_pack: BN affine (no softplus) of last layer -> packed f16 (feeds feat gemm)
__global__ __launch_bounds__(256)
void bn_pack_kernel(const ushort_t* __restrict__ h16, const float* __restrict__ bnsum,
                    const float* __restrict__ gamma, const float* __restrict__ beta,
                    ushort_t* __restrict__ outP, int N, float invN)
{
    int i = blockIdx.x;
    int d = threadIdx.x;
    float mean = bnsum[d] * invN;
    float var = bnsum[D_ + d] * invN - mean * mean;
    float inv = 1.f / sqrtf(fmaxf(var, 0.f) + EPS_);
    float v = (h2f(h16[(size_t)i * D_ + d]) - mean) * inv * gamma[d] + beta[d];
    outP[pk_off(i, d, 8)] = f2h_bits(v);
}

// ---------------------------------------------------------------------------
// weight pack (R16): W fp32 [K][N] -> SINGLE f16 tiles (nb, kb), row = col n
// ---------------------------------------------------------------------------
__global__ __launch_bounds__(256)
void convert_w_pack(const float* __restrict__ W, ushort_t* __restrict__ dh,
                    int N, int nKB)
{
    int kb = blockIdx.x, nb = blockIdx.y;
    int n = threadIdx.x >> 1, half = threadIdx.x & 1;
#pragma unroll
    for (int j = 0; j < 2; ++j) {
        int kq = half * 2 + j;
        size_t o = (size_t)(nb * nKB + kb) * TILE_SH + kq * PLANE_SH + n * 8;
#pragma unroll
        for (int jj = 0; jj < 8; ++jj) {
            float w = W[(size_t)(kb * 32 + kq * 8 + jj) * N + nb * 128 + n];
            dh[o + jj] = f2h_bits(w);
        }
    }
}

// ---------------------------------------------------------------------------
// gemm_p16<EPI> [R17]: single-f16 A/B (R16) + XCD-aware 1-D grid swizzle:
//   id = grp*8*NB + nb*8 + (rb - grp*8)  =>  id%8 depends only on rb%8, so
//   all NB column siblings of one row-tile land on the SAME XCD (round-robin
//   dispatch) and share the A tile in that XCD's 4MB L2.
//   EPI 0: softplus -> packed f16 Tout (nKBo = N/32)
//   EPI 1: f16 row-major Tout[m][N] (raw h) + fused bn partial sums (N == 256)
//   EPI 2: run-merged atomicAdd into Cout[batch[gm]*N + gn]  (graph pool)
// 1-D grid ceil(mb/8)*8*NB; block 256 thr / 4 waves; tile 128x128; LDS 33.8 KB.
// ---------------------------------------------------------------------------
template <int EPI>
__global__ __launch_bounds__(256)
void gemm_p16(const ushort_t* __restrict__ APK, const ushort_t* __restrict__ BPK,
              const float* __restrict__ bias,
              ushort_t* __restrict__ Tout, float* __restrict__ Cout,
              float* __restrict__ bnsum, const int* __restrict__ batch,
              int m, int N, int nKB)
{
    __shared__ ushort_t lA[2 * TILE_SH], lB[2 * TILE_SH];   // 33.8 KB

    const int NB = N >> 7;
    const int mb = (m + 127) >> 7;
    int id = blockIdx.x;
    int grp = id / (8 * NB);
    int rem = id - grp * 8 * NB;
    int nb = rem >> 3;
    int rb = grp * 8 + (rem & 7);
    if (rb >= mb) return;   // uniform early-out (tail row-group)

    int tid = threadIdx.x, wave = tid >> 6, lane = tid & 63;
    int wr = wave >> 1, wc = wave & 1;
    int fr = lane & 15, kq = lane >> 4;

    f4v acc[4][4];
#pragma unroll
    for (int i = 0; i < 4; ++i)
#pragma unroll
        for (int j = 0; j < 4; ++j)
            acc[i][j] = (f4v){0.f, 0.f, 0.f, 0.f};

    for (int kb = 0; kb < nKB; kb += 2) {
        const ushort_t* as = APK + (size_t)(rb * nKB + kb) * TILE_SH;
        const ushort_t* bs = BPK + (size_t)(nb * nKB + kb) * TILE_SH;
        for (int c = tid; c < 1056; c += 256) {
            int base = (c - lane) * 8;   // wave-uniform LDS base
            gload_lds16(as + c * 8, lA + base);
            gload_lds16(bs + c * 8, lB + base);
        }
        __syncthreads();

#pragma unroll
        for (int sub = 0; sub < 2; ++sub) {
            const ushort_t* sA = lA + sub * TILE_SH;
            const ushort_t* sB = lB + sub * TILE_SH;
            h8v Af[4], Bf[4];
#pragma unroll
            for (int t = 0; t < 4; ++t) {
                int ao = kq * PLANE_SH + (wr * 64 + fr + t * 16) * 8;
                int bo = kq * PLANE_SH + (wc * 64 + fr + t * 16) * 8;
                Af[t] = *(const h8v*)(sA + ao);
                Bf[t] = *(const h8v*)(sB + bo);
            }
#pragma unroll
            for (int rt = 0; rt < 4; ++rt)
#pragma unroll
                for (int ct = 0; ct < 4; ++ct)
                    acc[rt][ct] = __builtin_amdgcn_mfma_f32_16x16x32_f16(Af[rt], Bf[ct], acc[rt][ct], 0, 0, 0);
        }
        __syncthreads();
    }

    // epilogue: C/D layout col = lane&15, row = (lane>>4)*4 + reg
    int gm00 = rb * 128 + wr * 64 + kq * 4;
    int gn0  = nb * 128 + wc * 64 + fr;
    int nKBo = N >> 5;
#pragma unroll
    for (int ct = 0; ct < 4; ++ct) {
        int gn = gn0 + ct * 16;
        float bv = bias[gn];
        float s = 0.f, ss = 0.f;
#pragma unroll
        for (int rt = 0; rt < 4; ++rt) {
            if (EPI == 2) {
                int bp = -1; float run = 0.f;
#pragma unroll
                for (int rr = 0; rr < 4; ++rr) {
                    int gm = gm00 + rt * 16 + rr;
                    if (gm >= m) continue;
                    float v = acc[rt][ct][rr] + bv;
                    int bg = batch[gm];
                    if (bg == bp) { run += v; }
                    else {
                        if (bp >= 0) atomicAdd(&Cout[(size_t)bp * N + gn], run);
                        bp = bg; run = v;
                    }
                }
                if (bp >= 0) atomicAdd(&Cout[(size_t)bp * N + gn], run);
            } else {
#pragma unroll
                for (int rr = 0; rr < 4; ++rr) {
                    int gm = gm00 + rt * 16 + rr;
                    if (gm >= m) continue;
                    float v = acc[rt][ct][rr] + bv;
                    if (EPI == 0) {
                        Tout[pk_off(gm, gn, nKBo)] = f2h_bits(sp(v));
                    } else {
                        Tout[(size_t)gm * N + gn] = f2h_bits(v);  // raw h, f16
                        s += v;
                        ss += v * v;
                    }
                }
            }
        }
        if (EPI == 1) {
            s  += __shfl_xor(s, 16);  s  += __shfl_xor(s, 32);
            ss += __shfl_xor(ss, 16); ss += __shfl_xor(ss, 32);
            if (kq == 0) {
                atomicAdd(&bnsum[gn], s);
                atomicAdd(&bnsum[D_ + gn], ss);
            }
        }
    }
}

// ---------------------------------------------------------------------------
__global__ __launch_bounds__(256)
void count_kernel(const int* __restrict__ batch, float* __restrict__ cnt, int N)
{
    int i = blockIdx.x * 256 + threadIdx.x;
    if (i < N) atomicAdd(&cnt[batch[i]], 1.f);
}

__global__ __launch_bounds__(256)
void pool_div_kernel(float* __restrict__ gfeat, const float* __restrict__ cnt, int G)
{
    int g = blockIdx.x;
    float inv = 1.f / fmaxf(cnt[g], 1.f);
    for (int c = threadIdx.x; c < FD_; c += 256)
        gfeat[(size_t)g * FD_ + c] *= inv;
}

// ---------------------------------------------------------------------------
// fp32 GEMM for the small head: C = softplus(A @ W + bias)
// ---------------------------------------------------------------------------
#define BM 64
#define BN 64
#define BK 16

__global__ __launch_bounds__(256)
void gemm_head(const float* __restrict__ A, const float* __restrict__ W,
               const float* __restrict__ bias, float* __restrict__ C,
               int M, int N, int K)
{
    __shared__ float As[BK][BM + 4];
    __shared__ float Ws[BK][BN + 4];

    int tid = threadIdx.x;
    int bm = blockIdx.y * BM;
    int bn = blockIdx.x * BN;
    int tx = tid & 15;
    int ty = tid >> 4;

    float acc[4][4] = {};

    int a_m = tid >> 2;
    int a_k = (tid & 3) * 4;
    int w_k = tid >> 4;
    int w_n = (tid & 15) * 4;

    for (int k0 = 0; k0 < K; k0 += BK) {
        int gm = bm + a_m;
        float4 av = make_float4(0.f, 0.f, 0.f, 0.f);
        if (gm < M)
            av = *(const float4*)(A + (size_t)gm * K + k0 + a_k);
        As[a_k + 0][a_m] = av.x;
        As[a_k + 1][a_m] = av.y;
        As[a_k + 2][a_m] = av.z;
        As[a_k + 3][a_m] = av.w;

        float4 wv = *(const float4*)(W + (size_t)(k0 + w_k) * N + bn + w_n);
        *(float4*)&Ws[w_k][w_n] = wv;

        __syncthreads();

#pragma unroll
        for (int k = 0; k < BK; ++k) {
            float4 a4 = *(const float4*)&As[k][ty * 4];
            float4 b4 = *(const float4*)&Ws[k][tx * 4];
            float a[4] = {a4.x, a4.y, a4.z, a4.w};
            float b[4] = {b4.x, b4.y, b4.z, b4.w};
#pragma unroll
            for (int i = 0; i < 4; ++i)
#pragma unroll
                for (int j = 0; j < 4; ++j)
                    acc[i][j] += a[i] * b[j];
        }
        __syncthreads();
    }

#pragma unroll
    for (int i = 0; i < 4; ++i) {
        int gm = bm + ty * 4 + i;
        if (gm >= M) continue;
#pragma unroll
        for (int j = 0; j < 4; ++j) {
            int gn = bn + tx * 4 + j;
            C[(size_t)gm * N + gn] = sp(acc[i][j] + bias[gn]);
        }
    }
}

__global__ __launch_bounds__(256)
void head2_kernel(const float* __restrict__ hid, const float* __restrict__ w2,
                  const float* __restrict__ b2, float* __restrict__ out, int G)
{
    __shared__ float red[256];
    int g = blockIdx.x;
    int t = threadIdx.x;
    float v = hid[(size_t)g * 256 + t] * w2[t];
    red[t] = v;
    __syncthreads();
    for (int s = 128; s > 0; s >>= 1) {
        if (t < s) red[t] += red[t + s];
        __syncthreads();
    }
    if (t == 0) out[g] = red[0] + b2[0];
}

// ---------------------------------------------------------------------------
extern "C" void kernel_launch(void* const* d_in, const int* in_sizes, int n_in,
                              void* d_out, int out_size, void* d_ws, size_t ws_size,
                              hipStream_t stream)
{
    const int N = in_sizes[0];
    const int E = in_sizes[3];
    const int G = out_size;

    const int*   atomics  = (const int*)d_in[0];
    const float* pos      = (const float*)d_in[1];
    const int*   eidx     = (const int*)d_in[2];
    const int*   eattr    = (const int*)d_in[3];
    const int*   batch    = (const int*)d_in[4];
    const float* x_emb1   = (const float*)d_in[5];
    const float* x_emb2_w = (const float*)d_in[6];
    const float* x_emb2_b = (const float*)d_in[7];
    const float* edge_emb = (const float*)d_in[8];
    const float* mlp_w1   = (const float*)d_in[9];
    const float* mlp_b1   = (const float*)d_in[10];
    const float* mlp_w2   = (const float*)d_in[11];
    const float* mlp_b2   = (const float*)d_in[12];
    const float* bn_g     = (const float*)d_in[13];
    const float* bn_b     = (const float*)d_in[14];
    const float* feat_w   = (const float*)d_in[15];
    const float* feat_b   = (const float*)d_in[16];
    const float* head_w1  = (const float*)d_in[17];
    const float* head_b1  = (const float*)d_in[18];
    const float* head_w2  = (const float*)d_in[19];
    const float* head_b2  = (const float*)d_in[20];
    float* out = (float*)d_out;

    const int* src = eidx;
    const int* dst = eidx + E;

    char* ws = (char*)d_ws;
    size_t off = 0;
    auto carve = [&](size_t bytes) {
        void* p = ws + off;
        off += (bytes + 255) & ~(size_t)255;
        return p;
    };

    const int nRB = (N + 127) / 128;           // 128-row tiles

    // ---- fixed carve (~175 MB) ----
    ushort_t* h16  = (ushort_t*)carve((size_t)N * D_ * 2);             // 51.2 MB
    ushort_t* hact = (ushort_t*)carve((size_t)N * D_ * 2);             // 51.2 MB
    ushort_t* aggP = (ushort_t*)carve((size_t)nRB * 8 * TILE_SH * 2);  // 52.9 MB
    const size_t WTILES = 32 * TILE_SH;
    ushort_t* w1P = (ushort_t*)carve((size_t)L_ * WTILES * 2);
    ushort_t* w2P = (ushort_t*)carve((size_t)L_ * WTILES * 2);
    ushort_t* fP  = (ushort_t*)carve(WTILES * 2);
    float* bnsum  = (float*)carve(2 * D_ * 4);
    float* gfeat  = (float*)carve((size_t)G * FD_ * 4);                // 8.2 MB
    float* cnt    = (float*)carve((size_t)G * 4);
    float* hid    = (float*)carve((size_t)G * (FD_ / 2) * 4);
    // CSR buffers (~5 MB)
    int* cnt_i   = (int*)carve((size_t)N * 4);
    int* start_i = (int*)carve((size_t)N * 4);
    int* cursor  = (int*)carve((size_t)N * 4);
    int* total   = (int*)carve(4);
    uint32_t* elist = (uint32_t*)carve((size_t)E * 4);

    // ---- adaptive chunk for packed f16 T (16 tiles x 8448 B per 128 rows) ----
    size_t avail = (ws_size > off + 4096) ? (ws_size - off - 4096) : 0;
    long long mcb = (long long)(avail / (16 * (size_t)TILE_SH * 2));
    if (mcb > nRB) mcb = nRB;
    if (mcb < 16) mcb = 16;                    // floor (ws proven >= this)
    const int Mc = (int)(mcb * 128);
    ushort_t* tP = (ushort_t*)carve((size_t)mcb * 16 * TILE_SH * 2);

    const float invN = 1.f / (float)N;

    // ---- CSR build (once per launch, reused all 5 layers) ----
    hipMemsetAsync(cnt_i, 0, (size_t)N * 4, stream);
    hipMemsetAsync(total, 0, 4, stream);
    hist_kernel<<<(E + 255) / 256, 256, 0, stream>>>(dst, cnt_i, E);
    alloc_kernel<<<(N + 255) / 256, 256, 0, stream>>>(cnt_i, start_i, cursor, total, N);
    fill_kernel<<<(E + 255) / 256, 256, 0, stream>>>(src, dst, eattr, cursor, elist, E);

    // ---- one-time weight packing (single f16) ----
    for (int l = 0; l < L_; ++l) {
        convert_w_pack<<<dim3(8, 4), 256, 0, stream>>>(
            mlp_w1 + (size_t)l * D_ * FD_, w1P + (size_t)l * WTILES, FD_, 8);
        convert_w_pack<<<dim3(16, 2), 256, 0, stream>>>(
            mlp_w2 + (size_t)l * FD_ * D_, w2P + (size_t)l * WTILES, D_, 16);
    }
    convert_w_pack<<<dim3(8, 4), 256, 0, stream>>>(feat_w, fP, FD_, 8);

    init_h_kernel<<<N, 256, 0, stream>>>(atomics, pos, x_emb1, x_emb2_w, x_emb2_b, h16, N);

    const long long total8 = (long long)N * D_ / 8;
    const int ACTB = (int)((total8 + 255) / 256);
    const int GB4 = (N + 3) / 4;

    // swizzled 1-D grid sizes: ceil(mb/8)*8*NB
    auto swgrid = [](int mb, int NBc) { return ((mb + 7) / 8) * 8 * NBc; };

    for (int l = 0; l < L_; ++l) {
        const float* ee_l = edge_emb + (size_t)l * 2 * D_;
        const ushort_t* gsrc = h16;
        if (l > 0) {
            act16_kernel<<<ACTB, 256, 0, stream>>>(h16, hact, bnsum,
                bn_g + (size_t)(l - 1) * D_, bn_b + (size_t)(l - 1) * D_, total8, invN);
            gsrc = hact;
        }
        gather_pack4_kernel<<<GB4, 256, 0, stream>>>(gsrc, elist, start_i, cnt_i,
                                                     ee_l, aggP, N);

        hipMemsetAsync(bnsum, 0, 2 * D_ * 4, stream);
        for (int r0 = 0; r0 < N; r0 += Mc) {
            int m = min(Mc, N - r0);
            int mb = (m + 127) / 128;
            // T = sp(agg @ W1 + b1)  -> packed f16     [NB = 4]
            gemm_p16<0><<<swgrid(mb, 4), 256, 0, stream>>>(
                aggP + (size_t)(r0 >> 7) * 8 * TILE_SH,
                w1P + (size_t)l * WTILES,
                mlp_b1 + (size_t)l * FD_, tP, nullptr, nullptr, nullptr,
                m, FD_, 8);
            // h16 = f16(T @ W2 + b2) raw + bn stats    [NB = 2]
            gemm_p16<1><<<swgrid(mb, 2), 256, 0, stream>>>(
                tP, w2P + (size_t)l * WTILES,
                mlp_b2 + (size_t)l * D_, h16 + (size_t)r0 * D_, nullptr, bnsum, nullptr,
                m, D_, 16);
        }
    }

    // ---- feat + mean-pool: BN(h16) -> packed f16 (reuse aggP), pooled gemm ----
    bn_pack_kernel<<<N, 256, 0, stream>>>(h16, bnsum, bn_g + (size_t)(L_ - 1) * D_,
                                          bn_b + (size_t)(L_ - 1) * D_, aggP, N, invN);
    hipMemsetAsync(gfeat, 0, (size_t)G * FD_ * 4, stream);
    hipMemsetAsync(cnt, 0, (size_t)G * 4, stream);
    gemm_p16<2><<<swgrid(nRB, 4), 256, 0, stream>>>(
        aggP, fP, feat_b, nullptr, gfeat, nullptr, batch, N, FD_, 8);
    count_kernel<<<(N + 255) / 256, 256, 0, stream>>>(batch, cnt, N);
    pool_div_kernel<<<G, 256, 0, stream>>>(gfeat, cnt, G);

    // ---- head ----
    gemm_head<<<dim3((FD_ / 2) / BN, (G + BM - 1) / BM), 256, 0, stream>>>(
        gfeat, head_w1, head_b1, hid, G, FD_ / 2, FD_);
    head2_kernel<<<G, 256, 0, stream>>>(hid, head_w2, head_b2, out, G);
}